// Round 8
// baseline (144.214 us; speedup 1.0000x reference)
//
#include <hip/hip_runtime.h>
#include <math.h>

#define N_NODES 16384
#define DIM 256
#define KNBR 16
#define NEDGE 128
#define KZ 384            // z1 (256) | EZ (128)

typedef __bf16 bf16x8 __attribute__((ext_vector_type(8)));
typedef float f32x4 __attribute__((ext_vector_type(4)));
typedef short short8v __attribute__((ext_vector_type(8)));
typedef unsigned int u32;
typedef u32 u32x4 __attribute__((ext_vector_type(4)));
typedef unsigned short u16;

__device__ __forceinline__ u16 f2bf(float x) {
    u32 u = __builtin_bit_cast(u32, x);
    u = u + 0x7FFFu + ((u >> 16) & 1u);   // round-to-nearest-even
    return (u16)(u >> 16);
}
__device__ __forceinline__ float bf2f(u16 h) {
    u32 u = ((u32)h) << 16;
    return __builtin_bit_cast(float, u);
}

// XOR-swizzled LDS index (16B-unit swizzle) for a [rows][64] bf16 tile.
__device__ __forceinline__ int lds_swz(int row, int k) {
    return (row << 6) + ((((k >> 3) ^ (row & 7)) << 3) | (k & 7));
}

// ---------------------------------------------------------------------------
// pack_tables: Xh = bf16(X) [16384,256]; WnbTh2[c][k<256] = bf16(W_nb[k][c]);
// W1h[n][k] = bf16(W1[k][n]).  (WnbTh2 cols 256..383 = G, from build_MG.)
// ---------------------------------------------------------------------------
__global__ __launch_bounds__(256) void pack_tables(const float* __restrict__ X,
                                                   const float* __restrict__ W_nb,
                                                   const float* __restrict__ W1,
                                                   u16* __restrict__ Xh,
                                                   u16* __restrict__ WnbTh2,
                                                   u16* __restrict__ W1h) {
    const int XN = N_NODES * DIM;            // 4194304
    const int WE = DIM * DIM;                // 65536 (node cols of WnbTh2)
    const int WE1 = 64 * DIM;                // 16384
    const int TOT = XN + WE + WE1;
    for (int i = blockIdx.x * 256 + threadIdx.x; i < TOT; i += gridDim.x * 256) {
        if (i < XN) {
            Xh[i] = f2bf(X[i]);
        } else if (i < XN + WE) {
            int j = i - XN;                  // j = c*256 + k
            int c = j >> 8, k = j & 255;
            WnbTh2[c * KZ + k] = f2bf(W_nb[k * DIM + c]);
        } else {
            int j = i - XN - WE;             // j = n*256 + k, n<64
            int n = j >> 8, k = j & 255;
            W1h[j] = f2bf(W1[k * 64 + n]);
        }
    }
}

// ---------------------------------------------------------------------------
// build_MG (640 blocks):
//  j<256      : Mcat row j = (W_node @ attenW) row j, hi/lo bf16   (M1)
//  j in [256,512): M2f row (j-256) f32 (needed for EM)
//  j in [512,640): G[e=j-512][d] = sum_dd Eemb[e][dd]*W_nb[256+dd][d]
//                  -> WnbTh2[d][256+e]
// b_node is softmax-invariant -> dropped.
// ---------------------------------------------------------------------------
__global__ __launch_bounds__(256) void build_MG(const float* __restrict__ W_node,
                                                const float* __restrict__ attenW,
                                                const float* __restrict__ Eemb,
                                                const float* __restrict__ W_nb,
                                                u16* __restrict__ Mhi,
                                                u16* __restrict__ Mlo,
                                                float* __restrict__ M2f,
                                                u16* __restrict__ WnbTh2) {
    const int j = blockIdx.x;
    const int d = threadIdx.x;
    if (j < 512) {
        float acc = 0.f;
        for (int e = 0; e < DIM; ++e)
            acc = fmaf(W_node[j * DIM + e], attenW[e * DIM + d], acc);
        if (j < 256) {
            u16 h = f2bf(acc);
            Mhi[j * DIM + d] = h;
            Mlo[j * DIM + d] = f2bf(acc - bf2f(h));
        } else {
            M2f[(j - 256) * DIM + d] = acc;
        }
    } else {
        int e = j - 512;   // < 128
        float acc = 0.f;
        for (int dd = 0; dd < DIM; ++dd)
            acc = fmaf(Eemb[e * DIM + dd], W_nb[(DIM + dd) * DIM + d], acc);
        WnbTh2[d * KZ + DIM + e] = f2bf(acc);
    }
}

// ---------------------------------------------------------------------------
// build_EM (128 blocks): EM[e][d] = sum_j Eemb[e][j]*M2f[j][d]
// -> Mcat rows 256+e hi/lo.  (EZ = X @ EM^T gives e[oe]·z2 directly.)
// ---------------------------------------------------------------------------
__global__ __launch_bounds__(256) void build_EM(const float* __restrict__ Eemb,
                                                const float* __restrict__ M2f,
                                                u16* __restrict__ Mhi,
                                                u16* __restrict__ Mlo) {
    const int e = blockIdx.x;
    const int d = threadIdx.x;
    float acc = 0.f;
    for (int j = 0; j < DIM; ++j)
        acc = fmaf(Eemb[e * DIM + j], M2f[j * DIM + d], acc);
    u16 h = f2bf(acc);
    Mhi[(DIM + e) * DIM + d] = h;
    Mlo[(DIM + e) * DIM + d] = f2bf(acc - bf2f(h));
}

// ---------------------------------------------------------------------------
// gemm_z: [z1|EZ][16384,384] = Xh @ Mcat^T (hi+lo products).
// Epilogue: col<256 -> Zh bf16; col>=256 -> EZf f32.
// BM=128, BN=128, BK=64, 4 waves (2x2), mfma 16x16x32 bf16. Grid (128,3).
// ---------------------------------------------------------------------------
__global__ __launch_bounds__(256, 2) void gemm_z(const u16* __restrict__ Xh,
                                                 const u16* __restrict__ Mhi,
                                                 const u16* __restrict__ Mlo,
                                                 u16* __restrict__ Zh,
                                                 float* __restrict__ EZf) {
    constexpr int BM = 128, BN = 128, BK = 64;
    constexpr int Kd = DIM;
    __shared__ short Ah[BM * BK], Bh[BN * BK], Bl[BN * BK];
    const int tid = threadIdx.x;
    const int m0 = blockIdx.x * BM, n0 = blockIdx.y * BN;
    const int w = tid >> 6, lane = tid & 63;
    const int wr = (w >> 1) * 64, wc = (w & 1) * 64;
    const int lrow = lane & 15, lkg = lane >> 4;

    f32x4 acc[4][4] = {};

    for (int k0 = 0; k0 < Kd; k0 += BK) {
#pragma unroll
        for (int i = 0; i < 4; ++i) {
            int idx = i * 256 + tid;
            int r = idx >> 3, c8 = (idx & 7) << 3;
            int li = lds_swz(r, c8);
            *(short8v*)&Ah[li] = *(const short8v*)&Xh[(size_t)(m0 + r) * Kd + k0 + c8];
            *(short8v*)&Bh[li] = *(const short8v*)&Mhi[(size_t)(n0 + r) * Kd + k0 + c8];
            *(short8v*)&Bl[li] = *(const short8v*)&Mlo[(size_t)(n0 + r) * Kd + k0 + c8];
        }
        __syncthreads();
#pragma unroll
        for (int kk = 0; kk < 2; ++kk) {
            const int kof = kk * 32 + lkg * 8;
            bf16x8 a[4], bh[4], bl[4];
#pragma unroll
            for (int i = 0; i < 4; ++i) a[i] = *(const bf16x8*)&Ah[lds_swz(wr + i * 16 + lrow, kof)];
#pragma unroll
            for (int j = 0; j < 4; ++j) {
                bh[j] = *(const bf16x8*)&Bh[lds_swz(wc + j * 16 + lrow, kof)];
                bl[j] = *(const bf16x8*)&Bl[lds_swz(wc + j * 16 + lrow, kof)];
            }
#pragma unroll
            for (int i = 0; i < 4; ++i)
#pragma unroll
                for (int j = 0; j < 4; ++j) {
                    acc[i][j] = __builtin_amdgcn_mfma_f32_16x16x32_bf16(a[i], bh[j], acc[i][j], 0, 0, 0);
                    acc[i][j] = __builtin_amdgcn_mfma_f32_16x16x32_bf16(a[i], bl[j], acc[i][j], 0, 0, 0);
                }
        }
        __syncthreads();
    }
#pragma unroll
    for (int i = 0; i < 4; ++i)
#pragma unroll
        for (int j = 0; j < 4; ++j)
#pragma unroll
            for (int r = 0; r < 4; ++r) {
                int row = m0 + wr + i * 16 + lkg * 4 + r;
                int col = n0 + wc + j * 16 + lrow;
                if (col < DIM)
                    Zh[(size_t)row * DIM + col] = f2bf(acc[i][j][r]);
                else
                    EZf[(size_t)row * NEDGE + (col - DIM)] = acc[i][j][r];
            }
}

// ---------------------------------------------------------------------------
// attn_wt: ONE WAVE PER NODE. logit[k] = x[oi_k]·z1[n] + EZ[n][oe_k].
// 32-lane rows: load j handles k=2j (lanes 0-31) and k=2j+1 (lanes 32-63),
// 16B/lane. Butterfly-reduce 8 values over 32 lanes; softmax over masks
// {1,2,4,32}; wt -> wtbuf. No LDS, no barriers, small live set.
// ---------------------------------------------------------------------------
__global__ __launch_bounds__(256) void attn_wt(
    const u16* __restrict__ Xh, const u16* __restrict__ Zh,
    const float* __restrict__ EZf,
    const int* __restrict__ out_idx, const int* __restrict__ out_edge,
    const float* __restrict__ out_mask, float* __restrict__ wtbuf) {
    const int tid = threadIdx.x;
    const int w = tid >> 6, lane = tid & 63;
    const int n = blockIdx.x * 4 + w;
    const int nu = __builtin_amdgcn_readfirstlane(n);
    const int l31 = lane & 31, h = lane >> 5;

    int oi[KNBR];
#pragma unroll
    for (int k = 0; k < KNBR; ++k) oi[k] = out_idx[nu * KNBR + k];

    // z1 slice: lane covers dims [8*l31, 8*l31+8)
    float zr[8];
    {
        short8v zv = *(const short8v*)&Zh[(size_t)n * DIM + l31 * 8];
#pragma unroll
        for (int c = 0; c < 8; ++c) zr[c] = bf2f((u16)zv[c]);
    }

    const char* Xb = (const char*)Xh;
    const u32 lofs = (u32)l31 * 16u;

    float v[8];
#pragma unroll
    for (int j = 0; j < 8; ++j) {
        int ro = h ? oi[2 * j + 1] : oi[2 * j];
        u32x4 xv = *(const u32x4*)(Xb + (((u32)ro << 9) + lofs));
        short8v sv = __builtin_bit_cast(short8v, xv);
        float q = 0.f;
#pragma unroll
        for (int c = 0; c < 8; ++c) q = fmaf(bf2f((u16)sv[c]), zr[c], q);
        v[j] = q;
        if ((j & 3) == 3) __builtin_amdgcn_sched_barrier(0);
    }

    // butterfly: 8 values over 32 lanes -> lane holds sum for j = lane&7
    {
        const bool b0 = lane & 1;
#pragma unroll
        for (int i = 0; i < 4; ++i) {
            float keep = b0 ? v[2 * i + 1] : v[2 * i];
            float send = b0 ? v[2 * i] : v[2 * i + 1];
            v[i] = keep + __shfl_xor(send, 1);
        }
        const bool b1 = lane & 2;
#pragma unroll
        for (int i = 0; i < 2; ++i) {
            float keep = b1 ? v[2 * i + 1] : v[2 * i];
            float send = b1 ? v[2 * i] : v[2 * i + 1];
            v[i] = keep + __shfl_xor(send, 2);
        }
        const bool b2 = lane & 4;
        {
            float keep = b2 ? v[1] : v[0];
            float send = b2 ? v[0] : v[1];
            v[0] = keep + __shfl_xor(send, 4);
        }
    }
    float t = v[0];
    t += __shfl_xor(t, 8);
    t += __shfl_xor(t, 16);
    // t = node-part logit for k = 2*(lane&7) + h

    const int k_lane = ((lane & 7) << 1) | h;
    const int oe_v = out_edge[nu * KNBR + k_lane];
    t += EZf[(size_t)n * NEDGE + oe_v];

    // softmax over the 16 k's: reduce over masks {1,2,4,32}
    float m = t;
    m = fmaxf(m, __shfl_xor(m, 1));
    m = fmaxf(m, __shfl_xor(m, 2));
    m = fmaxf(m, __shfl_xor(m, 4));
    m = fmaxf(m, __shfl_xor(m, 32));
    float e = __expf(t - m);
    float s = e;
    s += __shfl_xor(s, 1);
    s += __shfl_xor(s, 2);
    s += __shfl_xor(s, 4);
    s += __shfl_xor(s, 32);
    const float om_v = out_mask[nu * KNBR + k_lane];
    const float wt = e / s * om_v;
    if ((lane & 24) == 0) wtbuf[n * KNBR + k_lane] = wt;
}

// ---------------------------------------------------------------------------
// aggregate: ONE WAVE PER NODE. Lanes 0-31 gather in-rows (x im), lanes
// 32-63 gather out-rows (x wt); fold halves; write REPnode bf16. Edge parts
// become a 128-bin histogram cnt (LDS atomicAdd, 32 adds) -> REPh cols
// 256..383 bf16. (cnt @ Eemb @ W_nb_lo folds into gemm_h via G.)
// ---------------------------------------------------------------------------
__global__ __launch_bounds__(256) void aggregate(
    const u16* __restrict__ Xh,
    const int* __restrict__ in_idx, const int* __restrict__ in_edge,
    const float* __restrict__ in_mask, const int* __restrict__ out_idx,
    const int* __restrict__ out_edge, const float* __restrict__ wtbuf,
    u16* __restrict__ REPh) {
    __shared__ float bins[4][NEDGE];
    const int tid = threadIdx.x;
    const int w = tid >> 6, lane = tid & 63;
    const int n = blockIdx.x * 4 + w;
    const int nu = __builtin_amdgcn_readfirstlane(n);
    const int l31 = lane & 31;
    const bool outside = lane >= 32;

    int oi[KNBR], ii[KNBR];
    float imb[KNBR], wtb[KNBR];
#pragma unroll
    for (int k = 0; k < KNBR; ++k) {
        oi[k] = out_idx[nu * KNBR + k];
        ii[k] = in_idx[nu * KNBR + k];
        imb[k] = in_mask[nu * KNBR + k];
        wtb[k] = wtbuf[nu * KNBR + k];
    }

    // zero histogram bins (per-wave private) before atomics
    bins[w][lane] = 0.f;
    bins[w][64 + lane] = 0.f;
    __syncthreads();

    const char* Xb = (const char*)Xh;
    const u32 lofs = (u32)l31 * 16u;

    float acc[8] = {};
#pragma unroll
    for (int k = 0; k < KNBR; ++k) {
        int row = outside ? oi[k] : ii[k];
        float sc = outside ? wtb[k] : imb[k];
        u32x4 xv = *(const u32x4*)(Xb + (((u32)row << 9) + lofs));
        short8v sv = __builtin_bit_cast(short8v, xv);
#pragma unroll
        for (int c = 0; c < 8; ++c) acc[c] = fmaf(sc, bf2f((u16)sv[c]), acc[c]);
        if ((k & 3) == 3) __builtin_amdgcn_sched_barrier(0);
    }
    // fold out-half into in-half
#pragma unroll
    for (int c = 0; c < 8; ++c) acc[c] += __shfl_xor(acc[c], 32);

    if (lane < 32) {
        short8v ov;
#pragma unroll
        for (int c = 0; c < 8; ++c) ov[c] = (short)f2bf(acc[c]);
        *(short8v*)&REPh[(size_t)n * KZ + l31 * 8] = ov;
    }

    // histogram: lanes 0-15 add (ie, im); lanes 16-31 add (oe, wt)
    {
        int lidx = nu * KNBR + (lane & 15);
        bool isout = (lane & 16) != 0;
        int eidx = isout ? out_edge[lidx] : in_edge[lidx];
        float ev = isout ? wtbuf[lidx] : in_mask[lidx];
        if (lane < 32) atomicAdd(&bins[w][eidx], ev);
    }
    __syncthreads();
    {
        u16 c0 = f2bf(bins[w][2 * lane]);
        u16 c1 = f2bf(bins[w][2 * lane + 1]);
        u32 pk = (u32)c0 | ((u32)c1 << 16);
        *(u32*)&REPh[(size_t)n * KZ + DIM + lane * 2] = pk;
    }
}

// ---------------------------------------------------------------------------
// gemm_h: out[16384,256] f32 = [REPnode|cnt] @ WnbTh2^T + X + 2*b_nb;
// also writes Hh bf16 (for the MFMA MLP). K=384. Grid (128,2).
// ---------------------------------------------------------------------------
__global__ __launch_bounds__(256, 3) void gemm_h(const u16* __restrict__ A,
                                                 const u16* __restrict__ B,
                                                 const float* __restrict__ X,
                                                 const float* __restrict__ b_nb,
                                                 float* __restrict__ out,
                                                 u16* __restrict__ Hh) {
    constexpr int BM = 128, BN = 128, BK = 64;
    constexpr int Kd = KZ, Nd = DIM;
    __shared__ short Ah[BM * BK], Bh[BN * BK];
    const int tid = threadIdx.x;
    const int m0 = blockIdx.x * BM, n0 = blockIdx.y * BN;
    const int w = tid >> 6, lane = tid & 63;
    const int wr = (w >> 1) * 64, wc = (w & 1) * 64;
    const int lrow = lane & 15, lkg = lane >> 4;

    f32x4 acc[4][4] = {};

    for (int k0 = 0; k0 < Kd; k0 += BK) {
#pragma unroll
        for (int i = 0; i < 4; ++i) {
            int idx = i * 256 + tid;
            int r = idx >> 3, c8 = (idx & 7) << 3;
            int li = lds_swz(r, c8);
            *(short8v*)&Ah[li] = *(const short8v*)&A[(size_t)(m0 + r) * Kd + k0 + c8];
            *(short8v*)&Bh[li] = *(const short8v*)&B[(size_t)(n0 + r) * Kd + k0 + c8];
        }
        __syncthreads();
#pragma unroll
        for (int kk = 0; kk < 2; ++kk) {
            const int kof = kk * 32 + lkg * 8;
            bf16x8 a[4], b[4];
#pragma unroll
            for (int i = 0; i < 4; ++i) a[i] = *(const bf16x8*)&Ah[lds_swz(wr + i * 16 + lrow, kof)];
#pragma unroll
            for (int j = 0; j < 4; ++j) b[j] = *(const bf16x8*)&Bh[lds_swz(wc + j * 16 + lrow, kof)];
#pragma unroll
            for (int i = 0; i < 4; ++i)
#pragma unroll
                for (int j = 0; j < 4; ++j)
                    acc[i][j] = __builtin_amdgcn_mfma_f32_16x16x32_bf16(a[i], b[j], acc[i][j], 0, 0, 0);
        }
        __syncthreads();
    }
#pragma unroll
    for (int i = 0; i < 4; ++i)
#pragma unroll
        for (int j = 0; j < 4; ++j)
#pragma unroll
            for (int r = 0; r < 4; ++r) {
                int row = m0 + wr + i * 16 + lkg * 4 + r;
                int col = n0 + wc + j * 16 + lrow;
                size_t off = (size_t)row * Nd + col;
                float hv = acc[i][j][r] + X[off] + 2.0f * b_nb[col];
                out[off] = hv;
                Hh[off] = f2bf(hv);
            }
}

// ---------------------------------------------------------------------------
// mlp_mfma + finalize: unchanged (deterministic 2-stage readout).
// ---------------------------------------------------------------------------
__global__ __launch_bounds__(256) void mlp_mfma(const u16* __restrict__ Hh,
                                                const u16* __restrict__ W1h,
                                                const float* __restrict__ b1,
                                                const float* __restrict__ W2,
                                                float* __restrict__ partials) {
    constexpr int BM = 128, BN = 64, BK = 64;
    constexpr int Kd = DIM;
    __shared__ short Ah[BM * BK], Bh[BN * BK];
    __shared__ float red[4][BN];
    const int tid = threadIdx.x;
    const int m0 = blockIdx.x * BM;
    const int w = tid >> 6, lane = tid & 63;
    const int wr = w * 32;
    const int lrow = lane & 15, lkg = lane >> 4;

    f32x4 acc[2][4] = {};

    for (int k0 = 0; k0 < Kd; k0 += BK) {
#pragma unroll
        for (int i = 0; i < 4; ++i) {
            int idx = i * 256 + tid;
            int r = idx >> 3, c8 = (idx & 7) << 3;
            *(short8v*)&Ah[lds_swz(r, c8)] =
                *(const short8v*)&Hh[(size_t)(m0 + r) * Kd + k0 + c8];
        }
#pragma unroll
        for (int i = 0; i < 2; ++i) {
            int idx = i * 256 + tid;
            if (idx < 512) {
                int r = idx >> 3, c8 = (idx & 7) << 3;
                *(short8v*)&Bh[lds_swz(r, c8)] =
                    *(const short8v*)&W1h[(size_t)r * Kd + k0 + c8];
            }
        }
        __syncthreads();
#pragma unroll
        for (int kk = 0; kk < 2; ++kk) {
            const int kof = kk * 32 + lkg * 8;
            bf16x8 a[2], b[4];
#pragma unroll
            for (int i = 0; i < 2; ++i) a[i] = *(const bf16x8*)&Ah[lds_swz(wr + i * 16 + lrow, kof)];
#pragma unroll
            for (int j = 0; j < 4; ++j) b[j] = *(const bf16x8*)&Bh[lds_swz(j * 16 + lrow, kof)];
#pragma unroll
            for (int i = 0; i < 2; ++i)
#pragma unroll
                for (int j = 0; j < 4; ++j)
                    acc[i][j] = __builtin_amdgcn_mfma_f32_16x16x32_bf16(a[i], b[j], acc[i][j], 0, 0, 0);
        }
        __syncthreads();
    }
    float cs[4];
#pragma unroll
    for (int j = 0; j < 4; ++j) {
        const float bj = b1[j * 16 + lrow];
        float sv = 0.f;
#pragma unroll
        for (int i = 0; i < 2; ++i)
#pragma unroll
            for (int r = 0; r < 4; ++r) sv += fmaxf(acc[i][j][r] + bj, 0.f);
        cs[j] = sv;
    }
#pragma unroll
    for (int j = 0; j < 4; ++j) {
        cs[j] += __shfl_xor(cs[j], 16);
        cs[j] += __shfl_xor(cs[j], 32);
    }
    if (lkg == 0) {
#pragma unroll
        for (int j = 0; j < 4; ++j) red[w][j * 16 + lrow] = cs[j];
    }
    __syncthreads();
    if (tid < 64) {
        float t = red[0][tid] + red[1][tid] + red[2][tid] + red[3][tid];
        float h0 = t * W2[tid * 2 + 0];
        float h1 = t * W2[tid * 2 + 1];
#pragma unroll
        for (int off = 32; off > 0; off >>= 1) {
            h0 += __shfl_down(h0, off);
            h1 += __shfl_down(h1, off);
        }
        if (tid == 0) {
            partials[blockIdx.x * 2 + 0] = h0;
            partials[blockIdx.x * 2 + 1] = h1;
        }
    }
}

__global__ void finalize(const float* __restrict__ partials,
                         const float* __restrict__ b2, float* __restrict__ out) {
    const int l = threadIdx.x;
    float h0 = 0.f, h1 = 0.f;
    for (int i = l; i < 128; i += 64) {
        h0 += partials[2 * i + 0];
        h1 += partials[2 * i + 1];
    }
#pragma unroll
    for (int off = 32; off > 0; off >>= 1) {
        h0 += __shfl_down(h0, off);
        h1 += __shfl_down(h1, off);
    }
    if (l == 0) {
        h0 += (float)N_NODES * b2[0];
        h1 += (float)N_NODES * b2[1];
        const float m = fmaxf(h0, h1);
        const float e0 = __expf(h0 - m), e1 = __expf(h1 - m);
        out[(size_t)N_NODES * DIM + 0] = e0 / (e0 + e1);
        out[(size_t)N_NODES * DIM + 1] = e1 / (e0 + e1);
    }
}

extern "C" void kernel_launch(void* const* d_in, const int* in_sizes, int n_in,
                              void* d_out, int out_size, void* d_ws, size_t ws_size,
                              hipStream_t stream) {
    const float* X = (const float*)d_in[0];
    const int* in_idx = (const int*)d_in[1];
    const int* in_edge = (const int*)d_in[2];
    const float* in_mask = (const float*)d_in[3];
    const int* out_idx = (const int*)d_in[4];
    const int* out_edge = (const int*)d_in[5];
    const float* out_mask = (const float*)d_in[6];
    const float* Eemb = (const float*)d_in[7];
    const float* W_nb = (const float*)d_in[8];
    const float* b_nb = (const float*)d_in[9];
    const float* W_node = (const float*)d_in[10];
    // d_in[11] = b_node: softmax-invariant -> unused
    const float* attenW = (const float*)d_in[12];
    const float* W1 = (const float*)d_in[13];
    const float* b1 = (const float*)d_in[14];
    const float* W2 = (const float*)d_in[15];
    const float* b2 = (const float*)d_in[16];
    float* out = (float*)d_out;

    char* ws = (char*)d_ws;
    // Overlays (stream-ordered): Zh+EZf dead after attn_wt -> REPh reuses;
    // Xh dead after aggregate -> Hh overlaps its head.
    u16* Zh = (u16*)ws;                          // 8 MiB  [0, 8M)
    float* EZf = (float*)(ws + 8388608);         // 8 MiB  [8M, 16M)
    u16* REPh = (u16*)ws;                        // 12.58 MiB [0, 12.58M)
    u16* Xh = (u16*)(ws + 16777216);             // 8 MiB  [16M, 24M)
    u16* Hh = (u16*)(ws + 12582912);             // 8 MiB  [12.58M, 20.97M)
    float* wtbuf = (float*)(ws + 25165824);      // 1 MiB
    u16* Mhi = (u16*)(ws + 26214400);            // 192 KiB (384x256)
    u16* Mlo = (u16*)(ws + 26411008);            // 192 KiB
    float* M2f = (float*)(ws + 26607616);        // 256 KiB
    u16* WnbTh2 = (u16*)(ws + 26869760);         // 192 KiB (256x384)
    u16* W1h = (u16*)(ws + 27066368);            // 32 KiB
    float* partials = (float*)(ws + 27099136);   // 1 KiB

    pack_tables<<<2048, 256, 0, stream>>>(X, W_nb, W1, Xh, WnbTh2, W1h);
    build_MG<<<640, 256, 0, stream>>>(W_node, attenW, Eemb, W_nb, Mhi, Mlo, M2f, WnbTh2);
    build_EM<<<128, 256, 0, stream>>>(Eemb, M2f, Mhi, Mlo);
    gemm_z<<<dim3(128, 3), 256, 0, stream>>>(Xh, Mhi, Mlo, Zh, EZf);
    attn_wt<<<N_NODES / 4, 256, 0, stream>>>(Xh, Zh, EZf, out_idx, out_edge,
                                             out_mask, wtbuf);
    aggregate<<<N_NODES / 4, 256, 0, stream>>>(Xh, in_idx, in_edge, in_mask,
                                               out_idx, out_edge, wtbuf, REPh);
    gemm_h<<<dim3(128, 2), 256, 0, stream>>>(REPh, WnbTh2, X, b_nb, out, Hh);
    mlp_mfma<<<N_NODES / 128, 256, 0, stream>>>(Hh, W1h, b1, W2, partials);
    finalize<<<1, 64, 0, stream>>>(partials, b2, out);
}

// Round 9
// 132.735 us; speedup vs baseline: 1.0865x; 1.0865x over previous
//
#include <hip/hip_runtime.h>
#include <math.h>

#define N_NODES 16384
#define DIM 256
#define KNBR 16
#define NEDGE 128
#define KZ 384            // REP layout: node (256) | edge-histogram (128)

typedef __bf16 bf16x8 __attribute__((ext_vector_type(8)));
typedef float f32x4 __attribute__((ext_vector_type(4)));
typedef short short8v __attribute__((ext_vector_type(8)));
typedef unsigned int u32;
typedef u32 u32x4 __attribute__((ext_vector_type(4)));
typedef unsigned short u16;

__device__ __forceinline__ u16 f2bf(float x) {
    u32 u = __builtin_bit_cast(u32, x);
    u = u + 0x7FFFu + ((u >> 16) & 1u);   // round-to-nearest-even
    return (u16)(u >> 16);
}
__device__ __forceinline__ float bf2f(u16 h) {
    u32 u = ((u32)h) << 16;
    return __builtin_bit_cast(float, u);
}

// XOR-swizzled LDS index (16B-unit swizzle) for a [rows][64] bf16 tile.
__device__ __forceinline__ int lds_swz(int row, int k) {
    return (row << 6) + ((((k >> 3) ^ (row & 7)) << 3) | (k & 7));
}

// ---------------------------------------------------------------------------
// pack_tables: Xh = bf16(X); WnbTh2[c][k<256] = bf16(W_nb[k][c]);
// W1h[n][k] = bf16(W1[k][n]).  (WnbTh2 cols 256..383 = G, from build_all.)
// ---------------------------------------------------------------------------
__global__ __launch_bounds__(256) void pack_tables(const float* __restrict__ X,
                                                   const float* __restrict__ W_nb,
                                                   const float* __restrict__ W1,
                                                   u16* __restrict__ Xh,
                                                   u16* __restrict__ WnbTh2,
                                                   u16* __restrict__ W1h) {
    const int XN = N_NODES * DIM;            // 4194304
    const int WE = DIM * DIM;                // 65536
    const int WE1 = 64 * DIM;                // 16384
    const int TOT = XN + WE + WE1;
    for (int i = blockIdx.x * 256 + threadIdx.x; i < TOT; i += gridDim.x * 256) {
        if (i < XN) {
            Xh[i] = f2bf(X[i]);
        } else if (i < XN + WE) {
            int j = i - XN;                  // j = c*256 + k
            int c = j >> 8, k = j & 255;
            WnbTh2[c * KZ + k] = f2bf(W_nb[k * DIM + c]);
        } else {
            int j = i - XN - WE;             // j = n*256 + k, n<64
            int n = j >> 8, k = j & 255;
            W1h[j] = f2bf(W1[k * 64 + n]);
        }
    }
}

// ---------------------------------------------------------------------------
// build_all (512 blocks):
//  j<256       : Mcat row j = (W_node @ attenW) row j, hi/lo bf16
//  j in [256,384): e=j-256: EM[e] = (Eemb[e] @ W_nodeL) @ attenW  (two-phase,
//                  F row in LDS) -> Mcat rows 256+e hi/lo
//  j in [384,512): e=j-384: G[e][d] = Eemb[e] @ W_nb[256:512,d]
//                  -> WnbTh2[d][256+e]
// b_node is softmax-invariant (constant over k) -> dropped.
// ---------------------------------------------------------------------------
__global__ __launch_bounds__(256) void build_all(const float* __restrict__ W_node,
                                                 const float* __restrict__ attenW,
                                                 const float* __restrict__ Eemb,
                                                 const float* __restrict__ W_nb,
                                                 u16* __restrict__ Mhi,
                                                 u16* __restrict__ Mlo,
                                                 u16* __restrict__ WnbTh2) {
    __shared__ float F[DIM];
    const int j = blockIdx.x;
    const int d = threadIdx.x;
    if (j < 256) {
        float acc = 0.f;
        for (int e = 0; e < DIM; ++e)
            acc = fmaf(W_node[j * DIM + e], attenW[e * DIM + d], acc);
        u16 h = f2bf(acc);
        Mhi[j * DIM + d] = h;
        Mlo[j * DIM + d] = f2bf(acc - bf2f(h));
    } else if (j < 384) {
        const int e = j - 256;
        float f = 0.f;
        for (int dd = 0; dd < DIM; ++dd)
            f = fmaf(Eemb[e * DIM + dd], W_node[(DIM + dd) * DIM + d], f);
        F[d] = f;
        __syncthreads();
        float acc = 0.f;
        for (int jj = 0; jj < DIM; ++jj)
            acc = fmaf(F[jj], attenW[jj * DIM + d], acc);
        u16 h = f2bf(acc);
        Mhi[(DIM + e) * DIM + d] = h;
        Mlo[(DIM + e) * DIM + d] = f2bf(acc - bf2f(h));
    } else {
        const int e = j - 384;
        float acc = 0.f;
        for (int dd = 0; dd < DIM; ++dd)
            acc = fmaf(Eemb[e * DIM + dd], W_nb[(DIM + dd) * DIM + d], acc);
        WnbTh2[d * KZ + DIM + e] = f2bf(acc);
    }
}

// ---------------------------------------------------------------------------
// gemm_z: [z1|EZ][16384,384] = Xh @ Mcat^T (hi+lo products).
// Epilogue: col<256 -> Zh bf16; col>=256 -> EZf f32.
// ---------------------------------------------------------------------------
__global__ __launch_bounds__(256, 2) void gemm_z(const u16* __restrict__ Xh,
                                                 const u16* __restrict__ Mhi,
                                                 const u16* __restrict__ Mlo,
                                                 u16* __restrict__ Zh,
                                                 float* __restrict__ EZf) {
    constexpr int BM = 128, BN = 128, BK = 64;
    constexpr int Kd = DIM;
    __shared__ short Ah[BM * BK], Bh[BN * BK], Bl[BN * BK];
    const int tid = threadIdx.x;
    const int m0 = blockIdx.x * BM, n0 = blockIdx.y * BN;
    const int w = tid >> 6, lane = tid & 63;
    const int wr = (w >> 1) * 64, wc = (w & 1) * 64;
    const int lrow = lane & 15, lkg = lane >> 4;

    f32x4 acc[4][4] = {};

    for (int k0 = 0; k0 < Kd; k0 += BK) {
#pragma unroll
        for (int i = 0; i < 4; ++i) {
            int idx = i * 256 + tid;
            int r = idx >> 3, c8 = (idx & 7) << 3;
            int li = lds_swz(r, c8);
            *(short8v*)&Ah[li] = *(const short8v*)&Xh[(size_t)(m0 + r) * Kd + k0 + c8];
            *(short8v*)&Bh[li] = *(const short8v*)&Mhi[(size_t)(n0 + r) * Kd + k0 + c8];
            *(short8v*)&Bl[li] = *(const short8v*)&Mlo[(size_t)(n0 + r) * Kd + k0 + c8];
        }
        __syncthreads();
#pragma unroll
        for (int kk = 0; kk < 2; ++kk) {
            const int kof = kk * 32 + lkg * 8;
            bf16x8 a[4], bh[4], bl[4];
#pragma unroll
            for (int i = 0; i < 4; ++i) a[i] = *(const bf16x8*)&Ah[lds_swz(wr + i * 16 + lrow, kof)];
#pragma unroll
            for (int j = 0; j < 4; ++j) {
                bh[j] = *(const bf16x8*)&Bh[lds_swz(wc + j * 16 + lrow, kof)];
                bl[j] = *(const bf16x8*)&Bl[lds_swz(wc + j * 16 + lrow, kof)];
            }
#pragma unroll
            for (int i = 0; i < 4; ++i)
#pragma unroll
                for (int j = 0; j < 4; ++j) {
                    acc[i][j] = __builtin_amdgcn_mfma_f32_16x16x32_bf16(a[i], bh[j], acc[i][j], 0, 0, 0);
                    acc[i][j] = __builtin_amdgcn_mfma_f32_16x16x32_bf16(a[i], bl[j], acc[i][j], 0, 0, 0);
                }
        }
        __syncthreads();
    }
#pragma unroll
    for (int i = 0; i < 4; ++i)
#pragma unroll
        for (int j = 0; j < 4; ++j)
#pragma unroll
            for (int r = 0; r < 4; ++r) {
                int row = m0 + wr + i * 16 + lkg * 4 + r;
                int col = n0 + wc + j * 16 + lrow;
                if (col < DIM)
                    Zh[(size_t)row * DIM + col] = f2bf(acc[i][j][r]);
                else
                    EZf[(size_t)row * NEDGE + (col - DIM)] = acc[i][j][r];
            }
}

// ---------------------------------------------------------------------------
// gather_fused: ONE WAVE PER NODE; no LDS, no barriers, no atomics, no stash.
// Attn: logit[k] = x[oi_k]·z1[n] + EZ[n][oe_k]; halves of the wave handle
// even/odd k (32-lane 16B row reads). Softmax in-wave. Aggregation: lanes
// 0-31 gather in-rows (x im), 32-63 out-rows (x wt); fold; write REPnode.
// Edge histogram IN REGISTERS: lane owns bins {2l, 2l+1}; the 32 (edge,val)
// pairs are wave-uniform (shfl-broadcast) -> 32 compare-selects.
// ---------------------------------------------------------------------------
__global__ __launch_bounds__(256) void gather_fused(
    const u16* __restrict__ Xh, const u16* __restrict__ Zh,
    const float* __restrict__ EZf,
    const int* __restrict__ in_idx, const int* __restrict__ in_edge,
    const float* __restrict__ in_mask, const int* __restrict__ out_idx,
    const int* __restrict__ out_edge, const float* __restrict__ out_mask,
    u16* __restrict__ REPh) {
    const int tid = threadIdx.x;
    const int w = tid >> 6, lane = tid & 63;
    const int n = blockIdx.x * 4 + w;
    const int nu = __builtin_amdgcn_readfirstlane(n);
    const int l31 = lane & 31, h = lane >> 5;

    // scalar index loads (wave-uniform -> SGPRs)
    int oi[KNBR], ii[KNBR];
#pragma unroll
    for (int k = 0; k < KNBR; ++k) {
        oi[k] = out_idx[nu * KNBR + k];
        ii[k] = in_idx[nu * KNBR + k];
    }

    // z1 slice: lane covers dims [8*l31, 8*l31+8)
    float zr[8];
    {
        short8v zv = *(const short8v*)&Zh[(size_t)n * DIM + l31 * 8];
#pragma unroll
        for (int c = 0; c < 8; ++c) zr[c] = bf2f((u16)zv[c]);
    }

    const char* Xb = (const char*)Xh;
    const u32 lofs = (u32)l31 * 16u;

    // attn: load j covers k=2j (lanes 0-31) and k=2j+1 (lanes 32-63)
    float v[8];
#pragma unroll
    for (int j = 0; j < 8; ++j) {
        int ro = h ? oi[2 * j + 1] : oi[2 * j];
        u32x4 xv = *(const u32x4*)(Xb + (((u32)ro << 9) + lofs));
        short8v sv = __builtin_bit_cast(short8v, xv);
        float q = 0.f;
#pragma unroll
        for (int c = 0; c < 8; ++c) q = fmaf(bf2f((u16)sv[c]), zr[c], q);
        v[j] = q;
        if ((j & 3) == 3) __builtin_amdgcn_sched_barrier(0);
    }

    // butterfly: 8 values over 32 lanes -> lane holds sum for j = lane&7
    {
        const bool b0 = lane & 1;
#pragma unroll
        for (int i = 0; i < 4; ++i) {
            float keep = b0 ? v[2 * i + 1] : v[2 * i];
            float send = b0 ? v[2 * i] : v[2 * i + 1];
            v[i] = keep + __shfl_xor(send, 1);
        }
        const bool b1 = lane & 2;
#pragma unroll
        for (int i = 0; i < 2; ++i) {
            float keep = b1 ? v[2 * i + 1] : v[2 * i];
            float send = b1 ? v[2 * i] : v[2 * i + 1];
            v[i] = keep + __shfl_xor(send, 2);
        }
        const bool b2 = lane & 4;
        {
            float keep = b2 ? v[1] : v[0];
            float send = b2 ? v[0] : v[1];
            v[0] = keep + __shfl_xor(send, 4);
        }
    }
    float t = v[0];
    t += __shfl_xor(t, 8);
    t += __shfl_xor(t, 16);
    // t = node-part logit for k_lane = 2*(lane&7) + h

    const int k_lane = ((lane & 7) << 1) | h;
    const int oe_v = out_edge[nu * KNBR + k_lane];
    const int ie_v = in_edge[nu * KNBR + k_lane];
    const float om_v = out_mask[nu * KNBR + k_lane];
    const float im_v = in_mask[nu * KNBR + k_lane];
    t += EZf[(size_t)n * NEDGE + oe_v];

    // softmax over the 16 k's: reduce over masks {1,2,4,32}
    float m = t;
    m = fmaxf(m, __shfl_xor(m, 1));
    m = fmaxf(m, __shfl_xor(m, 2));
    m = fmaxf(m, __shfl_xor(m, 4));
    m = fmaxf(m, __shfl_xor(m, 32));
    float e = __expf(t - m);
    float s = e;
    s += __shfl_xor(s, 1);
    s += __shfl_xor(s, 2);
    s += __shfl_xor(s, 4);
    s += __shfl_xor(s, 32);
    const float wt = e / s * om_v;   // lane holds weight for k_lane

    // aggregation: lanes 0-31 in-rows (x im), lanes 32-63 out-rows (x wt)
    const bool outside = lane >= 32;
    float acc[8] = {};
#pragma unroll
    for (int k = 0; k < KNBR; ++k) {
        const int lk = (k >> 1) | ((k & 1) << 5);   // lane holding k's scalars
        float wtk = __shfl(wt, lk);
        float imk = __shfl(im_v, lk);
        int row = outside ? oi[k] : ii[k];
        float sc = outside ? wtk : imk;
        u32x4 xv = *(const u32x4*)(Xb + (((u32)row << 9) + lofs));
        short8v sv = __builtin_bit_cast(short8v, xv);
#pragma unroll
        for (int c = 0; c < 8; ++c) acc[c] = fmaf(sc, bf2f((u16)sv[c]), acc[c]);
        if ((k & 3) == 3) __builtin_amdgcn_sched_barrier(0);
    }
#pragma unroll
    for (int c = 0; c < 8; ++c) acc[c] += __shfl_xor(acc[c], 32);

    if (lane < 32) {
        short8v ov;
#pragma unroll
        for (int c = 0; c < 8; ++c) ov[c] = (short)f2bf(acc[c]);
        *(short8v*)&REPh[(size_t)n * KZ + l31 * 8] = ov;
    }

    // in-register edge histogram: lane owns bins 2*lane, 2*lane+1
    float b0 = 0.f, b1 = 0.f;
    const int my0 = 2 * lane, my1 = 2 * lane + 1;
#pragma unroll
    for (int k = 0; k < KNBR; ++k) {
        const int lk = (k >> 1) | ((k & 1) << 5);
        float wtk = __shfl(wt, lk);
        float imk = __shfl(im_v, lk);
        int oek = __shfl(oe_v, lk);
        int iek = __shfl(ie_v, lk);
        b0 += (oek == my0 ? wtk : 0.f) + (iek == my0 ? imk : 0.f);
        b1 += (oek == my1 ? wtk : 0.f) + (iek == my1 ? imk : 0.f);
    }
    u32 pk = (u32)f2bf(b0) | ((u32)f2bf(b1) << 16);
    *(u32*)&REPh[(size_t)n * KZ + DIM + lane * 2] = pk;
}

// ---------------------------------------------------------------------------
// gemm_h: out[16384,256] f32 = [REPnode|cnt] @ WnbTh2^T + X + 2*b_nb;
// also writes Hh bf16 (for the MFMA MLP). K=384. Grid (128,2).
// ---------------------------------------------------------------------------
__global__ __launch_bounds__(256, 3) void gemm_h(const u16* __restrict__ A,
                                                 const u16* __restrict__ B,
                                                 const float* __restrict__ X,
                                                 const float* __restrict__ b_nb,
                                                 float* __restrict__ out,
                                                 u16* __restrict__ Hh) {
    constexpr int BM = 128, BN = 128, BK = 64;
    constexpr int Kd = KZ, Nd = DIM;
    __shared__ short Ah[BM * BK], Bh[BN * BK];
    const int tid = threadIdx.x;
    const int m0 = blockIdx.x * BM, n0 = blockIdx.y * BN;
    const int w = tid >> 6, lane = tid & 63;
    const int wr = (w >> 1) * 64, wc = (w & 1) * 64;
    const int lrow = lane & 15, lkg = lane >> 4;

    f32x4 acc[4][4] = {};

    for (int k0 = 0; k0 < Kd; k0 += BK) {
#pragma unroll
        for (int i = 0; i < 4; ++i) {
            int idx = i * 256 + tid;
            int r = idx >> 3, c8 = (idx & 7) << 3;
            int li = lds_swz(r, c8);
            *(short8v*)&Ah[li] = *(const short8v*)&A[(size_t)(m0 + r) * Kd + k0 + c8];
            *(short8v*)&Bh[li] = *(const short8v*)&B[(size_t)(n0 + r) * Kd + k0 + c8];
        }
        __syncthreads();
#pragma unroll
        for (int kk = 0; kk < 2; ++kk) {
            const int kof = kk * 32 + lkg * 8;
            bf16x8 a[4], b[4];
#pragma unroll
            for (int i = 0; i < 4; ++i) a[i] = *(const bf16x8*)&Ah[lds_swz(wr + i * 16 + lrow, kof)];
#pragma unroll
            for (int j = 0; j < 4; ++j) b[j] = *(const bf16x8*)&Bh[lds_swz(wc + j * 16 + lrow, kof)];
#pragma unroll
            for (int i = 0; i < 4; ++i)
#pragma unroll
                for (int j = 0; j < 4; ++j)
                    acc[i][j] = __builtin_amdgcn_mfma_f32_16x16x32_bf16(a[i], b[j], acc[i][j], 0, 0, 0);
        }
        __syncthreads();
    }
#pragma unroll
    for (int i = 0; i < 4; ++i)
#pragma unroll
        for (int j = 0; j < 4; ++j)
#pragma unroll
            for (int r = 0; r < 4; ++r) {
                int row = m0 + wr + i * 16 + lkg * 4 + r;
                int col = n0 + wc + j * 16 + lrow;
                size_t off = (size_t)row * Nd + col;
                float hv = acc[i][j][r] + X[off] + 2.0f * b_nb[col];
                out[off] = hv;
                Hh[off] = f2bf(hv);
            }
}

// ---------------------------------------------------------------------------
// mlp_mfma + finalize: unchanged (deterministic 2-stage readout).
// ---------------------------------------------------------------------------
__global__ __launch_bounds__(256) void mlp_mfma(const u16* __restrict__ Hh,
                                                const u16* __restrict__ W1h,
                                                const float* __restrict__ b1,
                                                const float* __restrict__ W2,
                                                float* __restrict__ partials) {
    constexpr int BM = 128, BN = 64, BK = 64;
    constexpr int Kd = DIM;
    __shared__ short Ah[BM * BK], Bh[BN * BK];
    __shared__ float red[4][BN];
    const int tid = threadIdx.x;
    const int m0 = blockIdx.x * BM;
    const int w = tid >> 6, lane = tid & 63;
    const int wr = w * 32;
    const int lrow = lane & 15, lkg = lane >> 4;

    f32x4 acc[2][4] = {};

    for (int k0 = 0; k0 < Kd; k0 += BK) {
#pragma unroll
        for (int i = 0; i < 4; ++i) {
            int idx = i * 256 + tid;
            int r = idx >> 3, c8 = (idx & 7) << 3;
            *(short8v*)&Ah[lds_swz(r, c8)] =
                *(const short8v*)&Hh[(size_t)(m0 + r) * Kd + k0 + c8];
        }
#pragma unroll
        for (int i = 0; i < 2; ++i) {
            int idx = i * 256 + tid;
            if (idx < 512) {
                int r = idx >> 3, c8 = (idx & 7) << 3;
                *(short8v*)&Bh[lds_swz(r, c8)] =
                    *(const short8v*)&W1h[(size_t)r * Kd + k0 + c8];
            }
        }
        __syncthreads();
#pragma unroll
        for (int kk = 0; kk < 2; ++kk) {
            const int kof = kk * 32 + lkg * 8;
            bf16x8 a[2], b[4];
#pragma unroll
            for (int i = 0; i < 2; ++i) a[i] = *(const bf16x8*)&Ah[lds_swz(wr + i * 16 + lrow, kof)];
#pragma unroll
            for (int j = 0; j < 4; ++j) b[j] = *(const bf16x8*)&Bh[lds_swz(j * 16 + lrow, kof)];
#pragma unroll
            for (int i = 0; i < 2; ++i)
#pragma unroll
                for (int j = 0; j < 4; ++j)
                    acc[i][j] = __builtin_amdgcn_mfma_f32_16x16x32_bf16(a[i], b[j], acc[i][j], 0, 0, 0);
        }
        __syncthreads();
    }
    float cs[4];
#pragma unroll
    for (int j = 0; j < 4; ++j) {
        const float bj = b1[j * 16 + lrow];
        float sv = 0.f;
#pragma unroll
        for (int i = 0; i < 2; ++i)
#pragma unroll
            for (int r = 0; r < 4; ++r) sv += fmaxf(acc[i][j][r] + bj, 0.f);
        cs[j] = sv;
    }
#pragma unroll
    for (int j = 0; j < 4; ++j) {
        cs[j] += __shfl_xor(cs[j], 16);
        cs[j] += __shfl_xor(cs[j], 32);
    }
    if (lkg == 0) {
#pragma unroll
        for (int j = 0; j < 4; ++j) red[w][j * 16 + lrow] = cs[j];
    }
    __syncthreads();
    if (tid < 64) {
        float t = red[0][tid] + red[1][tid] + red[2][tid] + red[3][tid];
        float h0 = t * W2[tid * 2 + 0];
        float h1 = t * W2[tid * 2 + 1];
#pragma unroll
        for (int off = 32; off > 0; off >>= 1) {
            h0 += __shfl_down(h0, off);
            h1 += __shfl_down(h1, off);
        }
        if (tid == 0) {
            partials[blockIdx.x * 2 + 0] = h0;
            partials[blockIdx.x * 2 + 1] = h1;
        }
    }
}

__global__ void finalize(const float* __restrict__ partials,
                         const float* __restrict__ b2, float* __restrict__ out) {
    const int l = threadIdx.x;
    float h0 = 0.f, h1 = 0.f;
    for (int i = l; i < 128; i += 64) {
        h0 += partials[2 * i + 0];
        h1 += partials[2 * i + 1];
    }
#pragma unroll
    for (int off = 32; off > 0; off >>= 1) {
        h0 += __shfl_down(h0, off);
        h1 += __shfl_down(h1, off);
    }
    if (l == 0) {
        h0 += (float)N_NODES * b2[0];
        h1 += (float)N_NODES * b2[1];
        const float m = fmaxf(h0, h1);
        const float e0 = __expf(h0 - m), e1 = __expf(h1 - m);
        out[(size_t)N_NODES * DIM + 0] = e0 / (e0 + e1);
        out[(size_t)N_NODES * DIM + 1] = e1 / (e0 + e1);
    }
}

extern "C" void kernel_launch(void* const* d_in, const int* in_sizes, int n_in,
                              void* d_out, int out_size, void* d_ws, size_t ws_size,
                              hipStream_t stream) {
    const float* X = (const float*)d_in[0];
    const int* in_idx = (const int*)d_in[1];
    const int* in_edge = (const int*)d_in[2];
    const float* in_mask = (const float*)d_in[3];
    const int* out_idx = (const int*)d_in[4];
    const int* out_edge = (const int*)d_in[5];
    const float* out_mask = (const float*)d_in[6];
    const float* Eemb = (const float*)d_in[7];
    const float* W_nb = (const float*)d_in[8];
    const float* b_nb = (const float*)d_in[9];
    const float* W_node = (const float*)d_in[10];
    // d_in[11] = b_node: softmax-invariant -> unused
    const float* attenW = (const float*)d_in[12];
    const float* W1 = (const float*)d_in[13];
    const float* b1 = (const float*)d_in[14];
    const float* W2 = (const float*)d_in[15];
    const float* b2 = (const float*)d_in[16];
    float* out = (float*)d_out;

    char* ws = (char*)d_ws;
    // Overlays (stream-ordered): Zh+EZf dead after gather_fused -> Hh reuses.
    u16* Zh = (u16*)ws;                          // 8 MiB   [0, 8M)
    float* EZf = (float*)(ws + 8388608);         // 8 MiB   [8M, 16M)
    u16* Hh = (u16*)ws;                          // 8 MiB   [0, 8M) reuse
    u16* REPh = (u16*)(ws + 16777216);           // 12.58 MiB
    u16* Xh = (u16*)(ws + 29360128);             // 8 MiB
    u16* WnbTh2 = (u16*)(ws + 37748736);         // 192 KiB (256x384)
    u16* Mhi = (u16*)(ws + 37945344);            // 192 KiB (384x256)
    u16* Mlo = (u16*)(ws + 38141952);            // 192 KiB
    u16* W1h = (u16*)(ws + 38338560);            // 32 KiB
    float* partials = (float*)(ws + 38371328);   // 1 KiB

    pack_tables<<<2048, 256, 0, stream>>>(X, W_nb, W1, Xh, WnbTh2, W1h);
    build_all<<<512, 256, 0, stream>>>(W_node, attenW, Eemb, W_nb, Mhi, Mlo, WnbTh2);
    gemm_z<<<dim3(128, 3), 256, 0, stream>>>(Xh, Mhi, Mlo, Zh, EZf);
    gather_fused<<<N_NODES / 4, 256, 0, stream>>>(Xh, Zh, EZf, in_idx, in_edge,
                                                  in_mask, out_idx, out_edge,
                                                  out_mask, REPh);
    gemm_h<<<dim3(128, 2), 256, 0, stream>>>(REPh, WnbTh2, X, b_nb, out, Hh);
    mlp_mfma<<<N_NODES / 128, 256, 0, stream>>>(Hh, W1h, b1, W2, partials);
    finalize<<<1, 64, 0, stream>>>(partials, b2, out);
}

// Round 10
// 130.709 us; speedup vs baseline: 1.1033x; 1.0155x over previous
//
#include <hip/hip_runtime.h>
#include <math.h>

#define N_NODES 16384
#define DIM 256
#define KNBR 16
#define NEDGE 128
#define KZ 384            // REP layout: node (256) | edge-histogram (128)

typedef __bf16 bf16x8 __attribute__((ext_vector_type(8)));
typedef float f32x4 __attribute__((ext_vector_type(4)));
typedef short short8v __attribute__((ext_vector_type(8)));
typedef unsigned int u32;
typedef u32 u32x4 __attribute__((ext_vector_type(4)));
typedef unsigned short u16;

__device__ __forceinline__ u16 f2bf(float x) {
    u32 u = __builtin_bit_cast(u32, x);
    u = u + 0x7FFFu + ((u >> 16) & 1u);   // round-to-nearest-even
    return (u16)(u >> 16);
}
__device__ __forceinline__ float bf2f(u16 h) {
    u32 u = ((u32)h) << 16;
    return __builtin_bit_cast(float, u);
}

// XOR-swizzled LDS index (16B-unit swizzle) for a [rows][64] bf16 tile.
__device__ __forceinline__ int lds_swz(int row, int k) {
    return (row << 6) + ((((k >> 3) ^ (row & 7)) << 3) | (k & 7));
}

// ---------------------------------------------------------------------------
// pack_tables: Xh = bf16(X); WnbTh2[c][k<256] = bf16(W_nb[k][c]);
// W1h[n][k] = bf16(W1[k][n]).  (WnbTh2 cols 256..383 = G, from build_all.)
// ---------------------------------------------------------------------------
__global__ __launch_bounds__(256) void pack_tables(const float* __restrict__ X,
                                                   const float* __restrict__ W_nb,
                                                   const float* __restrict__ W1,
                                                   u16* __restrict__ Xh,
                                                   u16* __restrict__ WnbTh2,
                                                   u16* __restrict__ W1h) {
    const int XN = N_NODES * DIM;            // 4194304
    const int WE = DIM * DIM;                // 65536
    const int WE1 = 64 * DIM;                // 16384
    const int TOT = XN + WE + WE1;
    for (int i = blockIdx.x * 256 + threadIdx.x; i < TOT; i += gridDim.x * 256) {
        if (i < XN) {
            Xh[i] = f2bf(X[i]);
        } else if (i < XN + WE) {
            int j = i - XN;                  // j = c*256 + k
            int c = j >> 8, k = j & 255;
            WnbTh2[c * KZ + k] = f2bf(W_nb[k * DIM + c]);
        } else {
            int j = i - XN - WE;             // j = n*256 + k, n<64
            int n = j >> 8, k = j & 255;
            W1h[j] = f2bf(W1[k * 64 + n]);
        }
    }
}

// ---------------------------------------------------------------------------
// build_all (512 blocks):
//  j<256       : Mcat row j = (W_node @ attenW) row j, hi/lo bf16
//  j in [256,384): e=j-256: EM[e] = (Eemb[e] @ W_nodeL) @ attenW  (two-phase,
//                  F row in LDS) -> Mcat rows 256+e hi/lo
//  j in [384,512): e=j-384: G[e][d] = Eemb[e] @ W_nb[256:512,d]
//                  -> WnbTh2[d][256+e]
// b_node is softmax-invariant (constant over k) -> dropped.
// ---------------------------------------------------------------------------
__global__ __launch_bounds__(256) void build_all(const float* __restrict__ W_node,
                                                 const float* __restrict__ attenW,
                                                 const float* __restrict__ Eemb,
                                                 const float* __restrict__ W_nb,
                                                 u16* __restrict__ Mhi,
                                                 u16* __restrict__ Mlo,
                                                 u16* __restrict__ WnbTh2) {
    __shared__ float F[DIM];
    const int j = blockIdx.x;
    const int d = threadIdx.x;
    if (j < 256) {
        float acc = 0.f;
        for (int e = 0; e < DIM; ++e)
            acc = fmaf(W_node[j * DIM + e], attenW[e * DIM + d], acc);
        u16 h = f2bf(acc);
        Mhi[j * DIM + d] = h;
        Mlo[j * DIM + d] = f2bf(acc - bf2f(h));
    } else if (j < 384) {
        const int e = j - 256;
        float f = 0.f;
        for (int dd = 0; dd < DIM; ++dd)
            f = fmaf(Eemb[e * DIM + dd], W_node[(DIM + dd) * DIM + d], f);
        F[d] = f;
        __syncthreads();
        float acc = 0.f;
        for (int jj = 0; jj < DIM; ++jj)
            acc = fmaf(F[jj], attenW[jj * DIM + d], acc);
        u16 h = f2bf(acc);
        Mhi[(DIM + e) * DIM + d] = h;
        Mlo[(DIM + e) * DIM + d] = f2bf(acc - bf2f(h));
    } else {
        const int e = j - 384;
        float acc = 0.f;
        for (int dd = 0; dd < DIM; ++dd)
            acc = fmaf(Eemb[e * DIM + dd], W_nb[(DIM + dd) * DIM + d], acc);
        WnbTh2[d * KZ + DIM + e] = f2bf(acc);
    }
}

// ---------------------------------------------------------------------------
// gemm_z: [z1|EZ][16384,384] = Xh @ Mcat^T (hi+lo products).
// Epilogue: col<256 -> Zh bf16; col>=256 -> EZf f32.
// ---------------------------------------------------------------------------
__global__ __launch_bounds__(256, 2) void gemm_z(const u16* __restrict__ Xh,
                                                 const u16* __restrict__ Mhi,
                                                 const u16* __restrict__ Mlo,
                                                 u16* __restrict__ Zh,
                                                 float* __restrict__ EZf) {
    constexpr int BM = 128, BN = 128, BK = 64;
    constexpr int Kd = DIM;
    __shared__ short Ah[BM * BK], Bh[BN * BK], Bl[BN * BK];
    const int tid = threadIdx.x;
    const int m0 = blockIdx.x * BM, n0 = blockIdx.y * BN;
    const int w = tid >> 6, lane = tid & 63;
    const int wr = (w >> 1) * 64, wc = (w & 1) * 64;
    const int lrow = lane & 15, lkg = lane >> 4;

    f32x4 acc[4][4] = {};

    for (int k0 = 0; k0 < Kd; k0 += BK) {
#pragma unroll
        for (int i = 0; i < 4; ++i) {
            int idx = i * 256 + tid;
            int r = idx >> 3, c8 = (idx & 7) << 3;
            int li = lds_swz(r, c8);
            *(short8v*)&Ah[li] = *(const short8v*)&Xh[(size_t)(m0 + r) * Kd + k0 + c8];
            *(short8v*)&Bh[li] = *(const short8v*)&Mhi[(size_t)(n0 + r) * Kd + k0 + c8];
            *(short8v*)&Bl[li] = *(const short8v*)&Mlo[(size_t)(n0 + r) * Kd + k0 + c8];
        }
        __syncthreads();
#pragma unroll
        for (int kk = 0; kk < 2; ++kk) {
            const int kof = kk * 32 + lkg * 8;
            bf16x8 a[4], bh[4], bl[4];
#pragma unroll
            for (int i = 0; i < 4; ++i) a[i] = *(const bf16x8*)&Ah[lds_swz(wr + i * 16 + lrow, kof)];
#pragma unroll
            for (int j = 0; j < 4; ++j) {
                bh[j] = *(const bf16x8*)&Bh[lds_swz(wc + j * 16 + lrow, kof)];
                bl[j] = *(const bf16x8*)&Bl[lds_swz(wc + j * 16 + lrow, kof)];
            }
#pragma unroll
            for (int i = 0; i < 4; ++i)
#pragma unroll
                for (int j = 0; j < 4; ++j) {
                    acc[i][j] = __builtin_amdgcn_mfma_f32_16x16x32_bf16(a[i], bh[j], acc[i][j], 0, 0, 0);
                    acc[i][j] = __builtin_amdgcn_mfma_f32_16x16x32_bf16(a[i], bl[j], acc[i][j], 0, 0, 0);
                }
        }
        __syncthreads();
    }
#pragma unroll
    for (int i = 0; i < 4; ++i)
#pragma unroll
        for (int j = 0; j < 4; ++j)
#pragma unroll
            for (int r = 0; r < 4; ++r) {
                int row = m0 + wr + i * 16 + lkg * 4 + r;
                int col = n0 + wc + j * 16 + lrow;
                if (col < DIM)
                    Zh[(size_t)row * DIM + col] = f2bf(acc[i][j][r]);
                else
                    EZf[(size_t)row * NEDGE + (col - DIM)] = acc[i][j][r];
            }
}

// ---------------------------------------------------------------------------
// gather_fused: ONE WAVE PER NODE; no LDS, no barriers, no atomics, no stash.
// R9 lesson: index arrays were promote-alloca'd to per-thread LDS (16KB,
// 5.5M bank conflicts) -> force SGPR with readfirstlane on each value.
// Histogram merged into aggregation loop; (oe,ie) and (im,wt) packed into one
// u32 each -> 2 shfls per k (was 4). Fences every 8 loads (8 in flight).
// ---------------------------------------------------------------------------
__global__ __launch_bounds__(256) void gather_fused(
    const u16* __restrict__ Xh, const u16* __restrict__ Zh,
    const float* __restrict__ EZf,
    const int* __restrict__ in_idx, const int* __restrict__ in_edge,
    const float* __restrict__ in_mask, const int* __restrict__ out_idx,
    const int* __restrict__ out_edge, const float* __restrict__ out_mask,
    u16* __restrict__ REPh) {
    const int tid = threadIdx.x;
    const int w = tid >> 6, lane = tid & 63;
    const int n = blockIdx.x * 4 + w;
    const int nu = __builtin_amdgcn_readfirstlane(n);
    const int l31 = lane & 31, h = lane >> 5;

    // wave-uniform indices, FORCED to SGPRs (readfirstlane kills LDS-promote)
    int oi[KNBR], ii[KNBR];
#pragma unroll
    for (int k = 0; k < KNBR; ++k) {
        oi[k] = __builtin_amdgcn_readfirstlane(out_idx[nu * KNBR + k]);
        ii[k] = __builtin_amdgcn_readfirstlane(in_idx[nu * KNBR + k]);
    }

    // z1 slice: lane covers dims [8*l31, 8*l31+8)
    float zr[8];
    {
        short8v zv = *(const short8v*)&Zh[(size_t)n * DIM + l31 * 8];
#pragma unroll
        for (int c = 0; c < 8; ++c) zr[c] = bf2f((u16)zv[c]);
    }

    const char* Xb = (const char*)Xh;
    const u32 lofs = (u32)l31 * 16u;

    // attn: load j covers k=2j (lanes 0-31) and k=2j+1 (lanes 32-63)
    float v[8];
#pragma unroll
    for (int j = 0; j < 8; ++j) {
        int ro = h ? oi[2 * j + 1] : oi[2 * j];
        u32x4 xv = *(const u32x4*)(Xb + (((u32)ro << 9) + lofs));
        short8v sv = __builtin_bit_cast(short8v, xv);
        float q = 0.f;
#pragma unroll
        for (int c = 0; c < 8; ++c) q = fmaf(bf2f((u16)sv[c]), zr[c], q);
        v[j] = q;
    }
    __builtin_amdgcn_sched_barrier(0);

    // butterfly: 8 values over 32 lanes -> lane holds sum for j = lane&7
    {
        const bool b0 = lane & 1;
#pragma unroll
        for (int i = 0; i < 4; ++i) {
            float keep = b0 ? v[2 * i + 1] : v[2 * i];
            float send = b0 ? v[2 * i] : v[2 * i + 1];
            v[i] = keep + __shfl_xor(send, 1);
        }
        const bool b1 = lane & 2;
#pragma unroll
        for (int i = 0; i < 2; ++i) {
            float keep = b1 ? v[2 * i + 1] : v[2 * i];
            float send = b1 ? v[2 * i] : v[2 * i + 1];
            v[i] = keep + __shfl_xor(send, 2);
        }
        const bool b2 = lane & 4;
        {
            float keep = b2 ? v[1] : v[0];
            float send = b2 ? v[0] : v[1];
            v[0] = keep + __shfl_xor(send, 4);
        }
    }
    float t = v[0];
    t += __shfl_xor(t, 8);
    t += __shfl_xor(t, 16);
    // t = node-part logit for k_lane = 2*(lane&7) + h

    const int k_lane = ((lane & 7) << 1) | h;
    const int oe_v = out_edge[nu * KNBR + k_lane];
    const int ie_v = in_edge[nu * KNBR + k_lane];
    const float om_v = out_mask[nu * KNBR + k_lane];
    const float im_v = in_mask[nu * KNBR + k_lane];
    t += EZf[(size_t)n * NEDGE + oe_v];

    // softmax over the 16 k's: reduce over masks {1,2,4,32}
    float m = t;
    m = fmaxf(m, __shfl_xor(m, 1));
    m = fmaxf(m, __shfl_xor(m, 2));
    m = fmaxf(m, __shfl_xor(m, 4));
    m = fmaxf(m, __shfl_xor(m, 32));
    float e = __expf(t - m);
    float s = e;
    s += __shfl_xor(s, 1);
    s += __shfl_xor(s, 2);
    s += __shfl_xor(s, 4);
    s += __shfl_xor(s, 32);
    const float wt = e / s * om_v;   // lane holds weight for k_lane

    // packed per-k payloads for single-shfl broadcast
    const u32 pkIdx = (u32)oe_v | ((u32)ie_v << 16);
    const u32 pkVal = (u32)f2bf(im_v) | ((u32)f2bf(wt) << 16);

    // merged aggregation + edge histogram
    const bool outside = lane >= 32;
    const int my0 = 2 * lane, my1 = 2 * lane + 1;
    float acc[8] = {};
    float hb0 = 0.f, hb1 = 0.f;
#pragma unroll
    for (int k = 0; k < KNBR; ++k) {
        const int lk = (k & 1) * 32 + (k >> 1);   // lane holding k's payload
        u32 pi = (u32)__shfl((int)pkIdx, lk);
        u32 pv = (u32)__shfl((int)pkVal, lk);
        float imk = bf2f((u16)(pv & 0xFFFFu));
        float wtk = bf2f((u16)(pv >> 16));
        int oek = (int)(pi & 0xFFFFu), iek = (int)(pi >> 16);
        int row = outside ? oi[k] : ii[k];
        float sc = outside ? wtk : imk;
        u32x4 xv = *(const u32x4*)(Xb + (((u32)row << 9) + lofs));
        short8v sv = __builtin_bit_cast(short8v, xv);
#pragma unroll
        for (int c = 0; c < 8; ++c) acc[c] = fmaf(sc, bf2f((u16)sv[c]), acc[c]);
        hb0 += (oek == my0 ? wtk : 0.f) + (iek == my0 ? imk : 0.f);
        hb1 += (oek == my1 ? wtk : 0.f) + (iek == my1 ? imk : 0.f);
        if ((k & 7) == 7) __builtin_amdgcn_sched_barrier(0);
    }
#pragma unroll
    for (int c = 0; c < 8; ++c) acc[c] += __shfl_xor(acc[c], 32);

    if (lane < 32) {
        short8v ov;
#pragma unroll
        for (int c = 0; c < 8; ++c) ov[c] = (short)f2bf(acc[c]);
        *(short8v*)&REPh[(size_t)n * KZ + l31 * 8] = ov;
    }
    u32 pk = (u32)f2bf(hb0) | ((u32)f2bf(hb1) << 16);
    *(u32*)&REPh[(size_t)n * KZ + DIM + lane * 2] = pk;
}

// ---------------------------------------------------------------------------
// gemm_h: out[16384,256] f32 = [REPnode|cnt] @ WnbTh2^T + X + 2*b_nb;
// also writes Hh bf16 (for the MFMA MLP). K=384. Grid (128,2).
// ---------------------------------------------------------------------------
__global__ __launch_bounds__(256, 3) void gemm_h(const u16* __restrict__ A,
                                                 const u16* __restrict__ B,
                                                 const float* __restrict__ X,
                                                 const float* __restrict__ b_nb,
                                                 float* __restrict__ out,
                                                 u16* __restrict__ Hh) {
    constexpr int BM = 128, BN = 128, BK = 64;
    constexpr int Kd = KZ, Nd = DIM;
    __shared__ short Ah[BM * BK], Bh[BN * BK];
    const int tid = threadIdx.x;
    const int m0 = blockIdx.x * BM, n0 = blockIdx.y * BN;
    const int w = tid >> 6, lane = tid & 63;
    const int wr = (w >> 1) * 64, wc = (w & 1) * 64;
    const int lrow = lane & 15, lkg = lane >> 4;

    f32x4 acc[4][4] = {};

    for (int k0 = 0; k0 < Kd; k0 += BK) {
#pragma unroll
        for (int i = 0; i < 4; ++i) {
            int idx = i * 256 + tid;
            int r = idx >> 3, c8 = (idx & 7) << 3;
            int li = lds_swz(r, c8);
            *(short8v*)&Ah[li] = *(const short8v*)&A[(size_t)(m0 + r) * Kd + k0 + c8];
            *(short8v*)&Bh[li] = *(const short8v*)&B[(size_t)(n0 + r) * Kd + k0 + c8];
        }
        __syncthreads();
#pragma unroll
        for (int kk = 0; kk < 2; ++kk) {
            const int kof = kk * 32 + lkg * 8;
            bf16x8 a[4], b[4];
#pragma unroll
            for (int i = 0; i < 4; ++i) a[i] = *(const bf16x8*)&Ah[lds_swz(wr + i * 16 + lrow, kof)];
#pragma unroll
            for (int j = 0; j < 4; ++j) b[j] = *(const bf16x8*)&Bh[lds_swz(wc + j * 16 + lrow, kof)];
#pragma unroll
            for (int i = 0; i < 4; ++i)
#pragma unroll
                for (int j = 0; j < 4; ++j)
                    acc[i][j] = __builtin_amdgcn_mfma_f32_16x16x32_bf16(a[i], b[j], acc[i][j], 0, 0, 0);
        }
        __syncthreads();
    }
#pragma unroll
    for (int i = 0; i < 4; ++i)
#pragma unroll
        for (int j = 0; j < 4; ++j)
#pragma unroll
            for (int r = 0; r < 4; ++r) {
                int row = m0 + wr + i * 16 + lkg * 4 + r;
                int col = n0 + wc + j * 16 + lrow;
                size_t off = (size_t)row * Nd + col;
                float hv = acc[i][j][r] + X[off] + 2.0f * b_nb[col];
                out[off] = hv;
                Hh[off] = f2bf(hv);
            }
}

// ---------------------------------------------------------------------------
// mlp_mfma + finalize: unchanged (deterministic 2-stage readout).
// ---------------------------------------------------------------------------
__global__ __launch_bounds__(256) void mlp_mfma(const u16* __restrict__ Hh,
                                                const u16* __restrict__ W1h,
                                                const float* __restrict__ b1,
                                                const float* __restrict__ W2,
                                                float* __restrict__ partials) {
    constexpr int BM = 128, BN = 64, BK = 64;
    constexpr int Kd = DIM;
    __shared__ short Ah[BM * BK], Bh[BN * BK];
    __shared__ float red[4][BN];
    const int tid = threadIdx.x;
    const int m0 = blockIdx.x * BM;
    const int w = tid >> 6, lane = tid & 63;
    const int wr = w * 32;
    const int lrow = lane & 15, lkg = lane >> 4;

    f32x4 acc[2][4] = {};

    for (int k0 = 0; k0 < Kd; k0 += BK) {
#pragma unroll
        for (int i = 0; i < 4; ++i) {
            int idx = i * 256 + tid;
            int r = idx >> 3, c8 = (idx & 7) << 3;
            *(short8v*)&Ah[lds_swz(r, c8)] =
                *(const short8v*)&Hh[(size_t)(m0 + r) * Kd + k0 + c8];
        }
#pragma unroll
        for (int i = 0; i < 2; ++i) {
            int idx = i * 256 + tid;
            if (idx < 512) {
                int r = idx >> 3, c8 = (idx & 7) << 3;
                *(short8v*)&Bh[lds_swz(r, c8)] =
                    *(const short8v*)&W1h[(size_t)r * Kd + k0 + c8];
            }
        }
        __syncthreads();
#pragma unroll
        for (int kk = 0; kk < 2; ++kk) {
            const int kof = kk * 32 + lkg * 8;
            bf16x8 a[2], b[4];
#pragma unroll
            for (int i = 0; i < 2; ++i) a[i] = *(const bf16x8*)&Ah[lds_swz(wr + i * 16 + lrow, kof)];
#pragma unroll
            for (int j = 0; j < 4; ++j) b[j] = *(const bf16x8*)&Bh[lds_swz(j * 16 + lrow, kof)];
#pragma unroll
            for (int i = 0; i < 2; ++i)
#pragma unroll
                for (int j = 0; j < 4; ++j)
                    acc[i][j] = __builtin_amdgcn_mfma_f32_16x16x32_bf16(a[i], b[j], acc[i][j], 0, 0, 0);
        }
        __syncthreads();
    }
    float cs[4];
#pragma unroll
    for (int j = 0; j < 4; ++j) {
        const float bj = b1[j * 16 + lrow];
        float sv = 0.f;
#pragma unroll
        for (int i = 0; i < 2; ++i)
#pragma unroll
            for (int r = 0; r < 4; ++r) sv += fmaxf(acc[i][j][r] + bj, 0.f);
        cs[j] = sv;
    }
#pragma unroll
    for (int j = 0; j < 4; ++j) {
        cs[j] += __shfl_xor(cs[j], 16);
        cs[j] += __shfl_xor(cs[j], 32);
    }
    if (lkg == 0) {
#pragma unroll
        for (int j = 0; j < 4; ++j) red[w][j * 16 + lrow] = cs[j];
    }
    __syncthreads();
    if (tid < 64) {
        float t = red[0][tid] + red[1][tid] + red[2][tid] + red[3][tid];
        float h0 = t * W2[tid * 2 + 0];
        float h1 = t * W2[tid * 2 + 1];
#pragma unroll
        for (int off = 32; off > 0; off >>= 1) {
            h0 += __shfl_down(h0, off);
            h1 += __shfl_down(h1, off);
        }
        if (tid == 0) {
            partials[blockIdx.x * 2 + 0] = h0;
            partials[blockIdx.x * 2 + 1] = h1;
        }
    }
}

__global__ void finalize(const float* __restrict__ partials,
                         const float* __restrict__ b2, float* __restrict__ out) {
    const int l = threadIdx.x;
    float h0 = 0.f, h1 = 0.f;
    for (int i = l; i < 128; i += 64) {
        h0 += partials[2 * i + 0];
        h1 += partials[2 * i + 1];
    }
#pragma unroll
    for (int off = 32; off > 0; off >>= 1) {
        h0 += __shfl_down(h0, off);
        h1 += __shfl_down(h1, off);
    }
    if (l == 0) {
        h0 += (float)N_NODES * b2[0];
        h1 += (float)N_NODES * b2[1];
        const float m = fmaxf(h0, h1);
        const float e0 = __expf(h0 - m), e1 = __expf(h1 - m);
        out[(size_t)N_NODES * DIM + 0] = e0 / (e0 + e1);
        out[(size_t)N_NODES * DIM + 1] = e1 / (e0 + e1);
    }
}

extern "C" void kernel_launch(void* const* d_in, const int* in_sizes, int n_in,
                              void* d_out, int out_size, void* d_ws, size_t ws_size,
                              hipStream_t stream) {
    const float* X = (const float*)d_in[0];
    const int* in_idx = (const int*)d_in[1];
    const int* in_edge = (const int*)d_in[2];
    const float* in_mask = (const float*)d_in[3];
    const int* out_idx = (const int*)d_in[4];
    const int* out_edge = (const int*)d_in[5];
    const float* out_mask = (const float*)d_in[6];
    const float* Eemb = (const float*)d_in[7];
    const float* W_nb = (const float*)d_in[8];
    const float* b_nb = (const float*)d_in[9];
    const float* W_node = (const float*)d_in[10];
    // d_in[11] = b_node: softmax-invariant -> unused
    const float* attenW = (const float*)d_in[12];
    const float* W1 = (const float*)d_in[13];
    const float* b1 = (const float*)d_in[14];
    const float* W2 = (const float*)d_in[15];
    const float* b2 = (const float*)d_in[16];
    float* out = (float*)d_out;

    char* ws = (char*)d_ws;
    // Overlays (stream-ordered): Zh+EZf dead after gather_fused -> Hh reuses.
    u16* Zh = (u16*)ws;                          // 8 MiB   [0, 8M)
    float* EZf = (float*)(ws + 8388608);         // 8 MiB   [8M, 16M)
    u16* Hh = (u16*)ws;                          // 8 MiB   [0, 8M) reuse
    u16* REPh = (u16*)(ws + 16777216);           // 12.58 MiB
    u16* Xh = (u16*)(ws + 29360128);             // 8 MiB
    u16* WnbTh2 = (u16*)(ws + 37748736);         // 192 KiB (256x384)
    u16* Mhi = (u16*)(ws + 37945344);            // 192 KiB (384x256)
    u16* Mlo = (u16*)(ws + 38141952);            // 192 KiB
    u16* W1h = (u16*)(ws + 38338560);            // 32 KiB
    float* partials = (float*)(ws + 38371328);   // 1 KiB

    pack_tables<<<2048, 256, 0, stream>>>(X, W_nb, W1, Xh, WnbTh2, W1h);
    build_all<<<512, 256, 0, stream>>>(W_node, attenW, Eemb, W_nb, Mhi, Mlo, WnbTh2);
    gemm_z<<<dim3(128, 3), 256, 0, stream>>>(Xh, Mhi, Mlo, Zh, EZf);
    gather_fused<<<N_NODES / 4, 256, 0, stream>>>(Xh, Zh, EZf, in_idx, in_edge,
                                                  in_mask, out_idx, out_edge,
                                                  out_mask, REPh);
    gemm_h<<<dim3(128, 2), 256, 0, stream>>>(REPh, WnbTh2, X, b_nb, out, Hh);
    mlp_mfma<<<N_NODES / 128, 256, 0, stream>>>(Hh, W1h, b1, W2, partials);
    finalize<<<1, 64, 0, stream>>>(partials, b2, out);
}

// Round 11
// 120.274 us; speedup vs baseline: 1.1990x; 1.0868x over previous
//
#include <hip/hip_runtime.h>
#include <math.h>

#define N_NODES 16384
#define DIM 256
#define KNBR 16
#define NEDGE 128
#define KZ 384            // REP layout: node (256) | edge-histogram (128)

typedef __bf16 bf16x8 __attribute__((ext_vector_type(8)));
typedef float f32x4 __attribute__((ext_vector_type(4)));
typedef short short8v __attribute__((ext_vector_type(8)));
typedef unsigned int u32;
typedef u32 u32x4 __attribute__((ext_vector_type(4)));
typedef unsigned short u16;

__device__ __forceinline__ u16 f2bf(float x) {
    u32 u = __builtin_bit_cast(u32, x);
    u = u + 0x7FFFu + ((u >> 16) & 1u);   // round-to-nearest-even
    return (u16)(u >> 16);
}
__device__ __forceinline__ float bf2f(u16 h) {
    u32 u = ((u32)h) << 16;
    return __builtin_bit_cast(float, u);
}

// XOR-swizzled LDS index (16B-unit swizzle) for a [rows][64] bf16 tile.
__device__ __forceinline__ int lds_swz(int row, int k) {
    return (row << 6) + ((((k >> 3) ^ (row & 7)) << 3) | (k & 7));
}

// ---------------------------------------------------------------------------
// pack_tables: Xh = bf16(X); WnbTh2[c][k<256] = bf16(W_nb[k][c]);
// W1h[n][k] = bf16(W1[k][n]).  (WnbTh2 cols 256..383 = G, from build_all.)
// ---------------------------------------------------------------------------
__global__ __launch_bounds__(256) void pack_tables(const float* __restrict__ X,
                                                   const float* __restrict__ W_nb,
                                                   const float* __restrict__ W1,
                                                   u16* __restrict__ Xh,
                                                   u16* __restrict__ WnbTh2,
                                                   u16* __restrict__ W1h) {
    const int XN = N_NODES * DIM;            // 4194304
    const int WE = DIM * DIM;                // 65536
    const int WE1 = 64 * DIM;                // 16384
    const int TOT = XN + WE + WE1;
    for (int i = blockIdx.x * 256 + threadIdx.x; i < TOT; i += gridDim.x * 256) {
        if (i < XN) {
            Xh[i] = f2bf(X[i]);
        } else if (i < XN + WE) {
            int j = i - XN;                  // j = c*256 + k
            int c = j >> 8, k = j & 255;
            WnbTh2[c * KZ + k] = f2bf(W_nb[k * DIM + c]);
        } else {
            int j = i - XN - WE;             // j = n*256 + k, n<64
            int n = j >> 8, k = j & 255;
            W1h[j] = f2bf(W1[k * 64 + n]);
        }
    }
}

// ---------------------------------------------------------------------------
// build_all (512 blocks):
//  j<256       : Mcat row j = (W_node @ attenW) row j, hi/lo bf16
//  j in [256,384): e=j-256: EM[e] = (Eemb[e] @ W_nodeL) @ attenW  (two-phase,
//                  F row in LDS) -> Mcat rows 256+e hi/lo
//  j in [384,512): e=j-384: G[e][d] = Eemb[e] @ W_nb[256:512,d]
//                  -> WnbTh2[d][256+e]
// b_node is softmax-invariant (constant over k) -> dropped.
// ---------------------------------------------------------------------------
__global__ __launch_bounds__(256) void build_all(const float* __restrict__ W_node,
                                                 const float* __restrict__ attenW,
                                                 const float* __restrict__ Eemb,
                                                 const float* __restrict__ W_nb,
                                                 u16* __restrict__ Mhi,
                                                 u16* __restrict__ Mlo,
                                                 u16* __restrict__ WnbTh2) {
    __shared__ float F[DIM];
    const int j = blockIdx.x;
    const int d = threadIdx.x;
    if (j < 256) {
        float acc = 0.f;
        for (int e = 0; e < DIM; ++e)
            acc = fmaf(W_node[j * DIM + e], attenW[e * DIM + d], acc);
        u16 h = f2bf(acc);
        Mhi[j * DIM + d] = h;
        Mlo[j * DIM + d] = f2bf(acc - bf2f(h));
    } else if (j < 384) {
        const int e = j - 256;
        float f = 0.f;
        for (int dd = 0; dd < DIM; ++dd)
            f = fmaf(Eemb[e * DIM + dd], W_node[(DIM + dd) * DIM + d], f);
        F[d] = f;
        __syncthreads();
        float acc = 0.f;
        for (int jj = 0; jj < DIM; ++jj)
            acc = fmaf(F[jj], attenW[jj * DIM + d], acc);
        u16 h = f2bf(acc);
        Mhi[(DIM + e) * DIM + d] = h;
        Mlo[(DIM + e) * DIM + d] = f2bf(acc - bf2f(h));
    } else {
        const int e = j - 384;
        float acc = 0.f;
        for (int dd = 0; dd < DIM; ++dd)
            acc = fmaf(Eemb[e * DIM + dd], W_nb[(DIM + dd) * DIM + d], acc);
        WnbTh2[d * KZ + DIM + e] = f2bf(acc);
    }
}

// ---------------------------------------------------------------------------
// gemm_z: [z1|EZ][16384,384] = Xh @ Mcat^T (hi+lo products).
// Epilogue: col<256 -> Zh bf16; col>=256 -> EZf f32.
// ---------------------------------------------------------------------------
__global__ __launch_bounds__(256, 2) void gemm_z(const u16* __restrict__ Xh,
                                                 const u16* __restrict__ Mhi,
                                                 const u16* __restrict__ Mlo,
                                                 u16* __restrict__ Zh,
                                                 float* __restrict__ EZf) {
    constexpr int BM = 128, BN = 128, BK = 64;
    constexpr int Kd = DIM;
    __shared__ short Ah[BM * BK], Bh[BN * BK], Bl[BN * BK];
    const int tid = threadIdx.x;
    const int m0 = blockIdx.x * BM, n0 = blockIdx.y * BN;
    const int w = tid >> 6, lane = tid & 63;
    const int wr = (w >> 1) * 64, wc = (w & 1) * 64;
    const int lrow = lane & 15, lkg = lane >> 4;

    f32x4 acc[4][4] = {};

    for (int k0 = 0; k0 < Kd; k0 += BK) {
#pragma unroll
        for (int i = 0; i < 4; ++i) {
            int idx = i * 256 + tid;
            int r = idx >> 3, c8 = (idx & 7) << 3;
            int li = lds_swz(r, c8);
            *(short8v*)&Ah[li] = *(const short8v*)&Xh[(size_t)(m0 + r) * Kd + k0 + c8];
            *(short8v*)&Bh[li] = *(const short8v*)&Mhi[(size_t)(n0 + r) * Kd + k0 + c8];
            *(short8v*)&Bl[li] = *(const short8v*)&Mlo[(size_t)(n0 + r) * Kd + k0 + c8];
        }
        __syncthreads();
#pragma unroll
        for (int kk = 0; kk < 2; ++kk) {
            const int kof = kk * 32 + lkg * 8;
            bf16x8 a[4], bh[4], bl[4];
#pragma unroll
            for (int i = 0; i < 4; ++i) a[i] = *(const bf16x8*)&Ah[lds_swz(wr + i * 16 + lrow, kof)];
#pragma unroll
            for (int j = 0; j < 4; ++j) {
                bh[j] = *(const bf16x8*)&Bh[lds_swz(wc + j * 16 + lrow, kof)];
                bl[j] = *(const bf16x8*)&Bl[lds_swz(wc + j * 16 + lrow, kof)];
            }
#pragma unroll
            for (int i = 0; i < 4; ++i)
#pragma unroll
                for (int j = 0; j < 4; ++j) {
                    acc[i][j] = __builtin_amdgcn_mfma_f32_16x16x32_bf16(a[i], bh[j], acc[i][j], 0, 0, 0);
                    acc[i][j] = __builtin_amdgcn_mfma_f32_16x16x32_bf16(a[i], bl[j], acc[i][j], 0, 0, 0);
                }
        }
        __syncthreads();
    }
#pragma unroll
    for (int i = 0; i < 4; ++i)
#pragma unroll
        for (int j = 0; j < 4; ++j)
#pragma unroll
            for (int r = 0; r < 4; ++r) {
                int row = m0 + wr + i * 16 + lkg * 4 + r;
                int col = n0 + wc + j * 16 + lrow;
                if (col < DIM)
                    Zh[(size_t)row * DIM + col] = f2bf(acc[i][j][r]);
                else
                    EZf[(size_t)row * NEDGE + (col - DIM)] = acc[i][j][r];
            }
}

// ---------------------------------------------------------------------------
// gather_fused v3: ONE WAVE PER NODE; ZERO local arrays (R9/R10 lesson: the
// 16-int index arrays were promote-alloca'd to 16KB per-thread LDS with
// 32-way bank conflicts, 5.5M cycles). Indices loaded PER-LANE (lane k holds
// neighbor k) and extracted with readlane(var, imm) -> SGPR broadcast, no
// alloca, no ds ops in the hot loops. Payload broadcasts likewise readlane.
// ---------------------------------------------------------------------------
__global__ __launch_bounds__(256) void gather_fused(
    const u16* __restrict__ Xh, const u16* __restrict__ Zh,
    const float* __restrict__ EZf,
    const int* __restrict__ in_idx, const int* __restrict__ in_edge,
    const float* __restrict__ in_mask, const int* __restrict__ out_idx,
    const int* __restrict__ out_edge, const float* __restrict__ out_mask,
    u16* __restrict__ REPh) {
    const int tid = threadIdx.x;
    const int w = tid >> 6, lane = tid & 63;
    const int n = blockIdx.x * 4 + w;
    const int nu = __builtin_amdgcn_readfirstlane(n);
    const int l31 = lane & 31, h = lane >> 5;
    const int l15 = lane & 15;

    // per-lane index load: lane (k mod 16) holds neighbor-k index
    const int oi_l = out_idx[nu * KNBR + l15];
    const int ii_l = in_idx[nu * KNBR + l15];

    // z1 slice: lane covers dims [8*l31, 8*l31+8)
    float zr[8];
    {
        short8v zvv = *(const short8v*)&Zh[(size_t)n * DIM + l31 * 8];
#pragma unroll
        for (int c = 0; c < 8; ++c) zr[c] = bf2f((u16)zvv[c]);
    }

    const char* Xb = (const char*)Xh;
    const u32 lofs = (u32)l31 * 16u;

    // attn: load j covers k=2j (lanes 0-31) and k=2j+1 (lanes 32-63)
    float v[8];
#pragma unroll
    for (int j = 0; j < 8; ++j) {
        const int ro0 = __builtin_amdgcn_readlane(oi_l, 2 * j);
        const int ro1 = __builtin_amdgcn_readlane(oi_l, 2 * j + 1);
        const int ro = h ? ro1 : ro0;
        u32x4 xv = *(const u32x4*)(Xb + (((u32)ro << 9) + lofs));
        short8v sv = __builtin_bit_cast(short8v, xv);
        float q = 0.f;
#pragma unroll
        for (int c = 0; c < 8; ++c) q = fmaf(bf2f((u16)sv[c]), zr[c], q);
        v[j] = q;
    }
    __builtin_amdgcn_sched_barrier(0);

    // butterfly: 8 values over 32 lanes -> lane holds sum for j = lane&7
    {
        const bool b0 = lane & 1;
#pragma unroll
        for (int i = 0; i < 4; ++i) {
            float keep = b0 ? v[2 * i + 1] : v[2 * i];
            float send = b0 ? v[2 * i] : v[2 * i + 1];
            v[i] = keep + __shfl_xor(send, 1);
        }
        const bool b1 = lane & 2;
#pragma unroll
        for (int i = 0; i < 2; ++i) {
            float keep = b1 ? v[2 * i + 1] : v[2 * i];
            float send = b1 ? v[2 * i] : v[2 * i + 1];
            v[i] = keep + __shfl_xor(send, 2);
        }
        const bool b2 = lane & 4;
        {
            float keep = b2 ? v[1] : v[0];
            float send = b2 ? v[0] : v[1];
            v[0] = keep + __shfl_xor(send, 4);
        }
    }
    float t = v[0];
    t += __shfl_xor(t, 8);
    t += __shfl_xor(t, 16);
    // t = node-part logit for k_lane = 2*(lane&7) + h

    const int k_lane = ((lane & 7) << 1) | h;
    const int oe_v = out_edge[nu * KNBR + k_lane];
    const int ie_v = in_edge[nu * KNBR + k_lane];
    const float om_v = out_mask[nu * KNBR + k_lane];
    const float im_v = in_mask[nu * KNBR + k_lane];
    t += EZf[(size_t)n * NEDGE + oe_v];

    // softmax over the 16 k's: reduce over masks {1,2,4,32}
    float m = t;
    m = fmaxf(m, __shfl_xor(m, 1));
    m = fmaxf(m, __shfl_xor(m, 2));
    m = fmaxf(m, __shfl_xor(m, 4));
    m = fmaxf(m, __shfl_xor(m, 32));
    float e = __expf(t - m);
    float s = e;
    s += __shfl_xor(s, 1);
    s += __shfl_xor(s, 2);
    s += __shfl_xor(s, 4);
    s += __shfl_xor(s, 32);
    const float wt = e / s * om_v;   // lane holds weight for k_lane

    // packed per-k payloads; broadcast below via readlane (imm lane, SALU)
    const u32 pkIdx = (u32)oe_v | ((u32)ie_v << 16);
    const u32 pkVal = (u32)f2bf(im_v) | ((u32)f2bf(wt) << 16);

    // merged aggregation + edge histogram (all broadcasts via readlane imm)
    const bool outside = lane >= 32;
    const int my0 = 2 * lane, my1 = 2 * lane + 1;
    float acc[8] = {};
    float hb0 = 0.f, hb1 = 0.f;
#pragma unroll
    for (int k = 0; k < KNBR; ++k) {
        constexpr int lkTab = 0;  (void)lkTab;
        const int lk = (k & 1) * 32 + (k >> 1);   // lane holding k's payload
        const u32 pi = (u32)__builtin_amdgcn_readlane((int)pkIdx, lk);
        const u32 pv = (u32)__builtin_amdgcn_readlane((int)pkVal, lk);
        const int oik = __builtin_amdgcn_readlane(oi_l, k & 15);
        const int iik = __builtin_amdgcn_readlane(ii_l, k & 15);
        float imk = bf2f((u16)(pv & 0xFFFFu));
        float wtk = bf2f((u16)(pv >> 16));
        int oek = (int)(pi & 0xFFFFu), iek = (int)(pi >> 16);
        int row = outside ? oik : iik;
        float sc = outside ? wtk : imk;
        u32x4 xv = *(const u32x4*)(Xb + (((u32)row << 9) + lofs));
        short8v sv = __builtin_bit_cast(short8v, xv);
#pragma unroll
        for (int c = 0; c < 8; ++c) acc[c] = fmaf(sc, bf2f((u16)sv[c]), acc[c]);
        hb0 += (oek == my0 ? wtk : 0.f) + (iek == my0 ? imk : 0.f);
        hb1 += (oek == my1 ? wtk : 0.f) + (iek == my1 ? imk : 0.f);
        if ((k & 7) == 7) __builtin_amdgcn_sched_barrier(0);
    }
#pragma unroll
    for (int c = 0; c < 8; ++c) acc[c] += __shfl_xor(acc[c], 32);

    if (lane < 32) {
        short8v ov;
#pragma unroll
        for (int c = 0; c < 8; ++c) ov[c] = (short)f2bf(acc[c]);
        *(short8v*)&REPh[(size_t)n * KZ + l31 * 8] = ov;
    }
    u32 pk = (u32)f2bf(hb0) | ((u32)f2bf(hb1) << 16);
    *(u32*)&REPh[(size_t)n * KZ + DIM + lane * 2] = pk;
}

// ---------------------------------------------------------------------------
// gemm_h: out[16384,256] f32 = [REPnode|cnt] @ WnbTh2^T + X + 2*b_nb;
// also writes Hh bf16 (for the MFMA MLP). K=384. Grid (128,2).
// ---------------------------------------------------------------------------
__global__ __launch_bounds__(256, 3) void gemm_h(const u16* __restrict__ A,
                                                 const u16* __restrict__ B,
                                                 const float* __restrict__ X,
                                                 const float* __restrict__ b_nb,
                                                 float* __restrict__ out,
                                                 u16* __restrict__ Hh) {
    constexpr int BM = 128, BN = 128, BK = 64;
    constexpr int Kd = KZ, Nd = DIM;
    __shared__ short Ah[BM * BK], Bh[BN * BK];
    const int tid = threadIdx.x;
    const int m0 = blockIdx.x * BM, n0 = blockIdx.y * BN;
    const int w = tid >> 6, lane = tid & 63;
    const int wr = (w >> 1) * 64, wc = (w & 1) * 64;
    const int lrow = lane & 15, lkg = lane >> 4;

    f32x4 acc[4][4] = {};

    for (int k0 = 0; k0 < Kd; k0 += BK) {
#pragma unroll
        for (int i = 0; i < 4; ++i) {
            int idx = i * 256 + tid;
            int r = idx >> 3, c8 = (idx & 7) << 3;
            int li = lds_swz(r, c8);
            *(short8v*)&Ah[li] = *(const short8v*)&A[(size_t)(m0 + r) * Kd + k0 + c8];
            *(short8v*)&Bh[li] = *(const short8v*)&B[(size_t)(n0 + r) * Kd + k0 + c8];
        }
        __syncthreads();
#pragma unroll
        for (int kk = 0; kk < 2; ++kk) {
            const int kof = kk * 32 + lkg * 8;
            bf16x8 a[4], b[4];
#pragma unroll
            for (int i = 0; i < 4; ++i) a[i] = *(const bf16x8*)&Ah[lds_swz(wr + i * 16 + lrow, kof)];
#pragma unroll
            for (int j = 0; j < 4; ++j) b[j] = *(const bf16x8*)&Bh[lds_swz(wc + j * 16 + lrow, kof)];
#pragma unroll
            for (int i = 0; i < 4; ++i)
#pragma unroll
                for (int j = 0; j < 4; ++j)
                    acc[i][j] = __builtin_amdgcn_mfma_f32_16x16x32_bf16(a[i], b[j], acc[i][j], 0, 0, 0);
        }
        __syncthreads();
    }
#pragma unroll
    for (int i = 0; i < 4; ++i)
#pragma unroll
        for (int j = 0; j < 4; ++j)
#pragma unroll
            for (int r = 0; r < 4; ++r) {
                int row = m0 + wr + i * 16 + lkg * 4 + r;
                int col = n0 + wc + j * 16 + lrow;
                size_t off = (size_t)row * Nd + col;
                float hv = acc[i][j][r] + X[off] + 2.0f * b_nb[col];
                out[off] = hv;
                Hh[off] = f2bf(hv);
            }
}

// ---------------------------------------------------------------------------
// mlp_mfma + finalize: unchanged (deterministic 2-stage readout).
// ---------------------------------------------------------------------------
__global__ __launch_bounds__(256) void mlp_mfma(const u16* __restrict__ Hh,
                                                const u16* __restrict__ W1h,
                                                const float* __restrict__ b1,
                                                const float* __restrict__ W2,
                                                float* __restrict__ partials) {
    constexpr int BM = 128, BN = 64, BK = 64;
    constexpr int Kd = DIM;
    __shared__ short Ah[BM * BK], Bh[BN * BK];
    __shared__ float red[4][BN];
    const int tid = threadIdx.x;
    const int m0 = blockIdx.x * BM;
    const int w = tid >> 6, lane = tid & 63;
    const int wr = w * 32;
    const int lrow = lane & 15, lkg = lane >> 4;

    f32x4 acc[2][4] = {};

    for (int k0 = 0; k0 < Kd; k0 += BK) {
#pragma unroll
        for (int i = 0; i < 4; ++i) {
            int idx = i * 256 + tid;
            int r = idx >> 3, c8 = (idx & 7) << 3;
            *(short8v*)&Ah[lds_swz(r, c8)] =
                *(const short8v*)&Hh[(size_t)(m0 + r) * Kd + k0 + c8];
        }
#pragma unroll
        for (int i = 0; i < 2; ++i) {
            int idx = i * 256 + tid;
            if (idx < 512) {
                int r = idx >> 3, c8 = (idx & 7) << 3;
                *(short8v*)&Bh[lds_swz(r, c8)] =
                    *(const short8v*)&W1h[(size_t)r * Kd + k0 + c8];
            }
        }
        __syncthreads();
#pragma unroll
        for (int kk = 0; kk < 2; ++kk) {
            const int kof = kk * 32 + lkg * 8;
            bf16x8 a[2], b[4];
#pragma unroll
            for (int i = 0; i < 2; ++i) a[i] = *(const bf16x8*)&Ah[lds_swz(wr + i * 16 + lrow, kof)];
#pragma unroll
            for (int j = 0; j < 4; ++j) b[j] = *(const bf16x8*)&Bh[lds_swz(j * 16 + lrow, kof)];
#pragma unroll
            for (int i = 0; i < 2; ++i)
#pragma unroll
                for (int j = 0; j < 4; ++j)
                    acc[i][j] = __builtin_amdgcn_mfma_f32_16x16x32_bf16(a[i], b[j], acc[i][j], 0, 0, 0);
        }
        __syncthreads();
    }
    float cs[4];
#pragma unroll
    for (int j = 0; j < 4; ++j) {
        const float bj = b1[j * 16 + lrow];
        float sv = 0.f;
#pragma unroll
        for (int i = 0; i < 2; ++i)
#pragma unroll
            for (int r = 0; r < 4; ++r) sv += fmaxf(acc[i][j][r] + bj, 0.f);
        cs[j] = sv;
    }
#pragma unroll
    for (int j = 0; j < 4; ++j) {
        cs[j] += __shfl_xor(cs[j], 16);
        cs[j] += __shfl_xor(cs[j], 32);
    }
    if (lkg == 0) {
#pragma unroll
        for (int j = 0; j < 4; ++j) red[w][j * 16 + lrow] = cs[j];
    }
    __syncthreads();
    if (tid < 64) {
        float t = red[0][tid] + red[1][tid] + red[2][tid] + red[3][tid];
        float h0 = t * W2[tid * 2 + 0];
        float h1 = t * W2[tid * 2 + 1];
#pragma unroll
        for (int off = 32; off > 0; off >>= 1) {
            h0 += __shfl_down(h0, off);
            h1 += __shfl_down(h1, off);
        }
        if (tid == 0) {
            partials[blockIdx.x * 2 + 0] = h0;
            partials[blockIdx.x * 2 + 1] = h1;
        }
    }
}

__global__ void finalize(const float* __restrict__ partials,
                         const float* __restrict__ b2, float* __restrict__ out) {
    const int l = threadIdx.x;
    float h0 = 0.f, h1 = 0.f;
    for (int i = l; i < 128; i += 64) {
        h0 += partials[2 * i + 0];
        h1 += partials[2 * i + 1];
    }
#pragma unroll
    for (int off = 32; off > 0; off >>= 1) {
        h0 += __shfl_down(h0, off);
        h1 += __shfl_down(h1, off);
    }
    if (l == 0) {
        h0 += (float)N_NODES * b2[0];
        h1 += (float)N_NODES * b2[1];
        const float m = fmaxf(h0, h1);
        const float e0 = __expf(h0 - m), e1 = __expf(h1 - m);
        out[(size_t)N_NODES * DIM + 0] = e0 / (e0 + e1);
        out[(size_t)N_NODES * DIM + 1] = e1 / (e0 + e1);
    }
}

extern "C" void kernel_launch(void* const* d_in, const int* in_sizes, int n_in,
                              void* d_out, int out_size, void* d_ws, size_t ws_size,
                              hipStream_t stream) {
    const float* X = (const float*)d_in[0];
    const int* in_idx = (const int*)d_in[1];
    const int* in_edge = (const int*)d_in[2];
    const float* in_mask = (const float*)d_in[3];
    const int* out_idx = (const int*)d_in[4];
    const int* out_edge = (const int*)d_in[5];
    const float* out_mask = (const float*)d_in[6];
    const float* Eemb = (const float*)d_in[7];
    const float* W_nb = (const float*)d_in[8];
    const float* b_nb = (const float*)d_in[9];
    const float* W_node = (const float*)d_in[10];
    // d_in[11] = b_node: softmax-invariant -> unused
    const float* attenW = (const float*)d_in[12];
    const float* W1 = (const float*)d_in[13];
    const float* b1 = (const float*)d_in[14];
    const float* W2 = (const float*)d_in[15];
    const float* b2 = (const float*)d_in[16];
    float* out = (float*)d_out;

    char* ws = (char*)d_ws;
    // Overlays (stream-ordered): Zh+EZf dead after gather_fused -> Hh reuses.
    u16* Zh = (u16*)ws;                          // 8 MiB   [0, 8M)
    float* EZf = (float*)(ws + 8388608);         // 8 MiB   [8M, 16M)
    u16* Hh = (u16*)ws;                          // 8 MiB   [0, 8M) reuse
    u16* REPh = (u16*)(ws + 16777216);           // 12.58 MiB
    u16* Xh = (u16*)(ws + 29360128);             // 8 MiB
    u16* WnbTh2 = (u16*)(ws + 37748736);         // 192 KiB (256x384)
    u16* Mhi = (u16*)(ws + 37945344);            // 192 KiB (384x256)
    u16* Mlo = (u16*)(ws + 38141952);            // 192 KiB
    u16* W1h = (u16*)(ws + 38338560);            // 32 KiB
    float* partials = (float*)(ws + 38371328);   // 1 KiB

    pack_tables<<<2048, 256, 0, stream>>>(X, W_nb, W1, Xh, WnbTh2, W1h);
    build_all<<<512, 256, 0, stream>>>(W_node, attenW, Eemb, W_nb, Mhi, Mlo, WnbTh2);
    gemm_z<<<dim3(128, 3), 256, 0, stream>>>(Xh, Mhi, Mlo, Zh, EZf);
    gather_fused<<<N_NODES / 4, 256, 0, stream>>>(Xh, Zh, EZf, in_idx, in_edge,
                                                  in_mask, out_idx, out_edge,
                                                  out_mask, REPh);
    gemm_h<<<dim3(128, 2), 256, 0, stream>>>(REPh, WnbTh2, X, b_nb, out, Hh);
    mlp_mfma<<<N_NODES / 128, 256, 0, stream>>>(Hh, W1h, b1, W2, partials);
    finalize<<<1, 64, 0, stream>>>(partials, b2, out);
}

// Round 12
// 110.870 us; speedup vs baseline: 1.3008x; 1.0848x over previous
//
#include <hip/hip_runtime.h>
#include <math.h>

#define N_NODES 16384
#define DIM 256
#define KNBR 16
#define NEDGE 128
#define KZ 384            // REP layout: node (256) | edge-histogram (128)

typedef __bf16 bf16x8 __attribute__((ext_vector_type(8)));
typedef float f32x4 __attribute__((ext_vector_type(4)));
typedef short short8v __attribute__((ext_vector_type(8)));
typedef unsigned int u32;
typedef u32 u32x4 __attribute__((ext_vector_type(4)));
typedef unsigned short u16;

__device__ __forceinline__ u16 f2bf(float x) {
    u32 u = __builtin_bit_cast(u32, x);
    u = u + 0x7FFFu + ((u >> 16) & 1u);   // round-to-nearest-even
    return (u16)(u >> 16);
}
__device__ __forceinline__ float bf2f(u16 h) {
    u32 u = ((u32)h) << 16;
    return __builtin_bit_cast(float, u);
}
__device__ __forceinline__ float readlane_f(float v, int l) {
    return __builtin_bit_cast(float, __builtin_amdgcn_readlane(__builtin_bit_cast(int, v), l));
}

// XOR-swizzled LDS index (16B-unit swizzle) for a [rows][64] bf16 tile.
__device__ __forceinline__ int lds_swz(int row, int k) {
    return (row << 6) + ((((k >> 3) ^ (row & 7)) << 3) | (k & 7));
}

// ---------------------------------------------------------------------------
// prep (2560 blocks): merged pack_tables + build_all (block-range split).
//  b<256       : Mcat row b = (W_node @ attenW) row b, hi/lo bf16
//  b in [256,384): e=b-256: EM[e] = (Eemb[e] @ W_nodeL) @ attenW -> Mcat 256+e
//  b in [384,512): e=b-384: G[e][d] = Eemb[e] @ W_nb[256:512,d] -> WnbTh2 col 256+e
//  b>=512      : pack Xh = bf16(X); WnbTh2 node cols; W1h transpose
// b_node is softmax-invariant (constant over k) -> dropped.
// ---------------------------------------------------------------------------
__global__ __launch_bounds__(256) void prep(const float* __restrict__ X,
                                            const float* __restrict__ W_nb,
                                            const float* __restrict__ W1,
                                            const float* __restrict__ W_node,
                                            const float* __restrict__ attenW,
                                            const float* __restrict__ Eemb,
                                            u16* __restrict__ Xh,
                                            u16* __restrict__ WnbTh2,
                                            u16* __restrict__ W1h,
                                            u16* __restrict__ Mhi,
                                            u16* __restrict__ Mlo) {
    __shared__ float F[DIM];
    const int b = blockIdx.x;
    const int d = threadIdx.x;
    if (b < 256) {
        float acc = 0.f;
        for (int e = 0; e < DIM; ++e)
            acc = fmaf(W_node[b * DIM + e], attenW[e * DIM + d], acc);
        u16 h = f2bf(acc);
        Mhi[b * DIM + d] = h;
        Mlo[b * DIM + d] = f2bf(acc - bf2f(h));
    } else if (b < 384) {
        const int e = b - 256;
        float f = 0.f;
        for (int dd = 0; dd < DIM; ++dd)
            f = fmaf(Eemb[e * DIM + dd], W_node[(DIM + dd) * DIM + d], f);
        F[d] = f;
        __syncthreads();
        float acc = 0.f;
        for (int jj = 0; jj < DIM; ++jj)
            acc = fmaf(F[jj], attenW[jj * DIM + d], acc);
        u16 h = f2bf(acc);
        Mhi[(DIM + e) * DIM + d] = h;
        Mlo[(DIM + e) * DIM + d] = f2bf(acc - bf2f(h));
    } else if (b < 512) {
        const int e = b - 384;
        float acc = 0.f;
        for (int dd = 0; dd < DIM; ++dd)
            acc = fmaf(Eemb[e * DIM + dd], W_nb[(DIM + dd) * DIM + d], acc);
        WnbTh2[d * KZ + DIM + e] = f2bf(acc);
    } else {
        const int XN = N_NODES * DIM;        // 4194304
        const int WE = DIM * DIM;            // 65536
        const int WE1 = 64 * DIM;            // 16384
        const int TOT = XN + WE + WE1;
        for (int i = (b - 512) * 256 + d; i < TOT; i += 2048 * 256) {
            if (i < XN) {
                Xh[i] = f2bf(X[i]);
            } else if (i < XN + WE) {
                int j = i - XN;              // j = c*256 + k
                int c = j >> 8, k = j & 255;
                WnbTh2[c * KZ + k] = f2bf(W_nb[k * DIM + c]);
            } else {
                int j = i - XN - WE;         // j = n*256 + k, n<64
                int n = j >> 8, k = j & 255;
                W1h[j] = f2bf(W1[k * 64 + n]);
            }
        }
    }
}

// ---------------------------------------------------------------------------
// gemm_z: [z1|EZ][16384,384] = Xh @ Mcat^T (hi+lo products).
// Epilogue: col<256 -> Zh bf16; col>=256 -> EZf f32.
// ---------------------------------------------------------------------------
__global__ __launch_bounds__(256, 2) void gemm_z(const u16* __restrict__ Xh,
                                                 const u16* __restrict__ Mhi,
                                                 const u16* __restrict__ Mlo,
                                                 u16* __restrict__ Zh,
                                                 float* __restrict__ EZf) {
    constexpr int BM = 128, BN = 128, BK = 64;
    constexpr int Kd = DIM;
    __shared__ short Ah[BM * BK], Bh[BN * BK], Bl[BN * BK];
    const int tid = threadIdx.x;
    const int m0 = blockIdx.x * BM, n0 = blockIdx.y * BN;
    const int w = tid >> 6, lane = tid & 63;
    const int wr = (w >> 1) * 64, wc = (w & 1) * 64;
    const int lrow = lane & 15, lkg = lane >> 4;

    f32x4 acc[4][4] = {};

    for (int k0 = 0; k0 < Kd; k0 += BK) {
#pragma unroll
        for (int i = 0; i < 4; ++i) {
            int idx = i * 256 + tid;
            int r = idx >> 3, c8 = (idx & 7) << 3;
            int li = lds_swz(r, c8);
            *(short8v*)&Ah[li] = *(const short8v*)&Xh[(size_t)(m0 + r) * Kd + k0 + c8];
            *(short8v*)&Bh[li] = *(const short8v*)&Mhi[(size_t)(n0 + r) * Kd + k0 + c8];
            *(short8v*)&Bl[li] = *(const short8v*)&Mlo[(size_t)(n0 + r) * Kd + k0 + c8];
        }
        __syncthreads();
#pragma unroll
        for (int kk = 0; kk < 2; ++kk) {
            const int kof = kk * 32 + lkg * 8;
            bf16x8 a[4], bh[4], bl[4];
#pragma unroll
            for (int i = 0; i < 4; ++i) a[i] = *(const bf16x8*)&Ah[lds_swz(wr + i * 16 + lrow, kof)];
#pragma unroll
            for (int j = 0; j < 4; ++j) {
                bh[j] = *(const bf16x8*)&Bh[lds_swz(wc + j * 16 + lrow, kof)];
                bl[j] = *(const bf16x8*)&Bl[lds_swz(wc + j * 16 + lrow, kof)];
            }
#pragma unroll
            for (int i = 0; i < 4; ++i)
#pragma unroll
                for (int j = 0; j < 4; ++j) {
                    acc[i][j] = __builtin_amdgcn_mfma_f32_16x16x32_bf16(a[i], bh[j], acc[i][j], 0, 0, 0);
                    acc[i][j] = __builtin_amdgcn_mfma_f32_16x16x32_bf16(a[i], bl[j], acc[i][j], 0, 0, 0);
                }
        }
        __syncthreads();
    }
#pragma unroll
    for (int i = 0; i < 4; ++i)
#pragma unroll
        for (int j = 0; j < 4; ++j)
#pragma unroll
            for (int r = 0; r < 4; ++r) {
                int row = m0 + wr + i * 16 + lkg * 4 + r;
                int col = n0 + wc + j * 16 + lrow;
                if (col < DIM)
                    Zh[(size_t)row * DIM + col] = f2bf(acc[i][j][r]);
                else
                    EZf[(size_t)row * NEDGE + (col - DIM)] = acc[i][j][r];
            }
}

// ---------------------------------------------------------------------------
// gather_fused v4: ONE WAVE PER NODE; flash-style single pass over out-rows.
// No max-subtraction softmax: logit sigma ~11 (analytic), |logit| << 88 =
// f32 exp overflow bound, so e_k = expf(logit_k) directly; acc_out weighted
// in the SAME pass that computes the logit (row still in registers), divide
// by s at the end. 32 row-gathers/node (minimum) vs 48 in v3.
// Zero local arrays (R9/R10 lesson); all broadcasts via readlane(imm).
// ---------------------------------------------------------------------------
__global__ __launch_bounds__(256) void gather_fused(
    const u16* __restrict__ Xh, const u16* __restrict__ Zh,
    const float* __restrict__ EZf,
    const int* __restrict__ in_idx, const int* __restrict__ in_edge,
    const float* __restrict__ in_mask, const int* __restrict__ out_idx,
    const int* __restrict__ out_edge, const float* __restrict__ out_mask,
    u16* __restrict__ REPh) {
    const int tid = threadIdx.x;
    const int w = tid >> 6, lane = tid & 63;
    const int n = blockIdx.x * 4 + w;
    const int nu = __builtin_amdgcn_readfirstlane(n);
    const int l31 = lane & 31, h = lane >> 5;
    const int l15 = lane & 15;

    // per-lane table loads: lane l15 holds neighbor-l15 data (readlane source);
    // k_lane-mapped copies feed the histogram payload.
    const int oi_l = out_idx[nu * KNBR + l15];
    const int ii_l = in_idx[nu * KNBR + l15];
    const float om_l = out_mask[nu * KNBR + l15];
    const int k_lane = ((lane & 7) << 1) | h;
    const int oe_v = out_edge[nu * KNBR + k_lane];
    const int ie_v = in_edge[nu * KNBR + k_lane];
    const float om_v = out_mask[nu * KNBR + k_lane];
    const float im_v = in_mask[nu * KNBR + k_lane];
    const int oe_l = out_edge[nu * KNBR + l15];
    const float ez_l = EZf[(size_t)n * NEDGE + oe_l];   // EZ for k=l15

    // z1 slice: lane covers dims [8*l31, 8*l31+8)
    float zr[8];
    {
        short8v zvv = *(const short8v*)&Zh[(size_t)n * DIM + l31 * 8];
#pragma unroll
        for (int c = 0; c < 8; ++c) zr[c] = bf2f((u16)zvv[c]);
    }

    const char* Xb = (const char*)Xh;
    const u32 lofs = (u32)l31 * 16u;

    // fused attn + out-aggregation: iter j covers k=2j (lanes 0-31) and
    // k=2j+1 (lanes 32-63); row consumed for BOTH logit and aggregation.
    float acc_o[8] = {};
    float s_run = 0.f, esel = 0.f;
#pragma unroll
    for (int j = 0; j < 8; ++j) {
        const int ro0 = __builtin_amdgcn_readlane(oi_l, 2 * j);
        const int ro1 = __builtin_amdgcn_readlane(oi_l, 2 * j + 1);
        const int ro = h ? ro1 : ro0;
        u32x4 xv = *(const u32x4*)(Xb + (((u32)ro << 9) + lofs));
        short8v sv = __builtin_bit_cast(short8v, xv);
        float q = 0.f;
#pragma unroll
        for (int c = 0; c < 8; ++c) q = fmaf(bf2f((u16)sv[c]), zr[c], q);
        q += __shfl_xor(q, 1);
        q += __shfl_xor(q, 2);
        q += __shfl_xor(q, 4);
        q += __shfl_xor(q, 8);
        q += __shfl_xor(q, 16);
        const float ez0 = readlane_f(ez_l, 2 * j);
        const float ez1 = readlane_f(ez_l, 2 * j + 1);
        q += h ? ez1 : ez0;
        const float eo = __expf(q);              // unnormalized weight, own k
        const float ec = __shfl_xor(eo, 32);     // other half's e
        s_run += eo + ec;                        // adds e(2j)+e(2j+1) once
        if ((lane & 7) == j) esel = eo;          // keep e for k_lane
        const float om0 = readlane_f(om_l, 2 * j);
        const float om1 = readlane_f(om_l, 2 * j + 1);
        const float wgt = eo * (h ? om1 : om0);
#pragma unroll
        for (int c = 0; c < 8; ++c) acc_o[c] = fmaf(wgt, bf2f((u16)sv[c]), acc_o[c]);
    }
    const float inv_s = 1.0f / s_run;
    const float wt = esel * om_v * inv_s;        // alpha*om for k_lane (hist)
    const u32 pkIdx = (u32)oe_v | ((u32)ie_v << 16);
    const u32 pkVal = (u32)f2bf(im_v) | ((u32)f2bf(wt) << 16);

    // in-aggregation + edge histogram (lane owns bins 2l, 2l+1)
    float acc_i[8] = {};
    const int my0 = 2 * lane, my1 = 2 * lane + 1;
    float hb0 = 0.f, hb1 = 0.f;
#pragma unroll
    for (int j = 0; j < 8; ++j) {
        const int ri0 = __builtin_amdgcn_readlane(ii_l, 2 * j);
        const int ri1 = __builtin_amdgcn_readlane(ii_l, 2 * j + 1);
        const int ri = h ? ri1 : ri0;
        u32x4 xv = *(const u32x4*)(Xb + (((u32)ri << 9) + lofs));
        short8v sv = __builtin_bit_cast(short8v, xv);
        const u32 pi0 = (u32)__builtin_amdgcn_readlane((int)pkIdx, j);
        const u32 pv0 = (u32)__builtin_amdgcn_readlane((int)pkVal, j);
        const u32 pi1 = (u32)__builtin_amdgcn_readlane((int)pkIdx, 32 + j);
        const u32 pv1 = (u32)__builtin_amdgcn_readlane((int)pkVal, 32 + j);
        const float im0 = bf2f((u16)(pv0 & 0xFFFFu)), wt0 = bf2f((u16)(pv0 >> 16));
        const float im1 = bf2f((u16)(pv1 & 0xFFFFu)), wt1 = bf2f((u16)(pv1 >> 16));
        const float imk = h ? im1 : im0;
#pragma unroll
        for (int c = 0; c < 8; ++c) acc_i[c] = fmaf(imk, bf2f((u16)sv[c]), acc_i[c]);
        const int oe0 = (int)(pi0 & 0xFFFFu), ie0 = (int)(pi0 >> 16);
        const int oe1 = (int)(pi1 & 0xFFFFu), ie1 = (int)(pi1 >> 16);
        hb0 += (oe0 == my0 ? wt0 : 0.f) + (ie0 == my0 ? im0 : 0.f)
             + (oe1 == my0 ? wt1 : 0.f) + (ie1 == my0 ? im1 : 0.f);
        hb1 += (oe0 == my1 ? wt0 : 0.f) + (ie0 == my1 ? im0 : 0.f)
             + (oe1 == my1 ? wt1 : 0.f) + (ie1 == my1 ? im1 : 0.f);
    }

    // fold halves; REPnode = out/s + in, from lanes 0-31
#pragma unroll
    for (int c = 0; c < 8; ++c) {
        float to = acc_o[c] + __shfl_xor(acc_o[c], 32);
        float ti = acc_i[c] + __shfl_xor(acc_i[c], 32);
        acc_o[c] = to * inv_s + ti;
    }
    if (lane < 32) {
        short8v ov;
#pragma unroll
        for (int c = 0; c < 8; ++c) ov[c] = (short)f2bf(acc_o[c]);
        *(short8v*)&REPh[(size_t)n * KZ + l31 * 8] = ov;
    }
    u32 pk = (u32)f2bf(hb0) | ((u32)f2bf(hb1) << 16);
    *(u32*)&REPh[(size_t)n * KZ + DIM + lane * 2] = pk;
}

// ---------------------------------------------------------------------------
// gemm_h: out[16384,256] f32 = [REPnode|cnt] @ WnbTh2^T + X + 2*b_nb;
// also writes Hh bf16 (for the MFMA MLP). K=384. Grid (128,2).
// ---------------------------------------------------------------------------
__global__ __launch_bounds__(256, 3) void gemm_h(const u16* __restrict__ A,
                                                 const u16* __restrict__ B,
                                                 const float* __restrict__ X,
                                                 const float* __restrict__ b_nb,
                                                 float* __restrict__ out,
                                                 u16* __restrict__ Hh) {
    constexpr int BM = 128, BN = 128, BK = 64;
    constexpr int Kd = KZ, Nd = DIM;
    __shared__ short Ah[BM * BK], Bh[BN * BK];
    const int tid = threadIdx.x;
    const int m0 = blockIdx.x * BM, n0 = blockIdx.y * BN;
    const int w = tid >> 6, lane = tid & 63;
    const int wr = (w >> 1) * 64, wc = (w & 1) * 64;
    const int lrow = lane & 15, lkg = lane >> 4;

    f32x4 acc[4][4] = {};

    for (int k0 = 0; k0 < Kd; k0 += BK) {
#pragma unroll
        for (int i = 0; i < 4; ++i) {
            int idx = i * 256 + tid;
            int r = idx >> 3, c8 = (idx & 7) << 3;
            int li = lds_swz(r, c8);
            *(short8v*)&Ah[li] = *(const short8v*)&A[(size_t)(m0 + r) * Kd + k0 + c8];
            *(short8v*)&Bh[li] = *(const short8v*)&B[(size_t)(n0 + r) * Kd + k0 + c8];
        }
        __syncthreads();
#pragma unroll
        for (int kk = 0; kk < 2; ++kk) {
            const int kof = kk * 32 + lkg * 8;
            bf16x8 a[4], b[4];
#pragma unroll
            for (int i = 0; i < 4; ++i) a[i] = *(const bf16x8*)&Ah[lds_swz(wr + i * 16 + lrow, kof)];
#pragma unroll
            for (int j = 0; j < 4; ++j) b[j] = *(const bf16x8*)&Bh[lds_swz(wc + j * 16 + lrow, kof)];
#pragma unroll
            for (int i = 0; i < 4; ++i)
#pragma unroll
                for (int j = 0; j < 4; ++j)
                    acc[i][j] = __builtin_amdgcn_mfma_f32_16x16x32_bf16(a[i], b[j], acc[i][j], 0, 0, 0);
        }
        __syncthreads();
    }
#pragma unroll
    for (int i = 0; i < 4; ++i)
#pragma unroll
        for (int j = 0; j < 4; ++j)
#pragma unroll
            for (int r = 0; r < 4; ++r) {
                int row = m0 + wr + i * 16 + lkg * 4 + r;
                int col = n0 + wc + j * 16 + lrow;
                size_t off = (size_t)row * Nd + col;
                float hv = acc[i][j][r] + X[off] + 2.0f * b_nb[col];
                out[off] = hv;
                Hh[off] = f2bf(hv);
            }
}

// ---------------------------------------------------------------------------
// mlp_mfma + finalize: unchanged (deterministic 2-stage readout).
// ---------------------------------------------------------------------------
__global__ __launch_bounds__(256) void mlp_mfma(const u16* __restrict__ Hh,
                                                const u16* __restrict__ W1h,
                                                const float* __restrict__ b1,
                                                const float* __restrict__ W2,
                                                float* __restrict__ partials) {
    constexpr int BM = 128, BN = 64, BK = 64;
    constexpr int Kd = DIM;
    __shared__ short Ah[BM * BK], Bh[BN * BK];
    __shared__ float red[4][BN];
    const int tid = threadIdx.x;
    const int m0 = blockIdx.x * BM;
    const int w = tid >> 6, lane = tid & 63;
    const int wr = w * 32;
    const int lrow = lane & 15, lkg = lane >> 4;

    f32x4 acc[2][4] = {};

    for (int k0 = 0; k0 < Kd; k0 += BK) {
#pragma unroll
        for (int i = 0; i < 4; ++i) {
            int idx = i * 256 + tid;
            int r = idx >> 3, c8 = (idx & 7) << 3;
            *(short8v*)&Ah[lds_swz(r, c8)] =
                *(const short8v*)&Hh[(size_t)(m0 + r) * Kd + k0 + c8];
        }
#pragma unroll
        for (int i = 0; i < 2; ++i) {
            int idx = i * 256 + tid;
            if (idx < 512) {
                int r = idx >> 3, c8 = (idx & 7) << 3;
                *(short8v*)&Bh[lds_swz(r, c8)] =
                    *(const short8v*)&W1h[(size_t)r * Kd + k0 + c8];
            }
        }
        __syncthreads();
#pragma unroll
        for (int kk = 0; kk < 2; ++kk) {
            const int kof = kk * 32 + lkg * 8;
            bf16x8 a[2], b[4];
#pragma unroll
            for (int i = 0; i < 2; ++i) a[i] = *(const bf16x8*)&Ah[lds_swz(wr + i * 16 + lrow, kof)];
#pragma unroll
            for (int j = 0; j < 4; ++j) b[j] = *(const bf16x8*)&Bh[lds_swz(j * 16 + lrow, kof)];
#pragma unroll
            for (int i = 0; i < 2; ++i)
#pragma unroll
                for (int j = 0; j < 4; ++j)
                    acc[i][j] = __builtin_amdgcn_mfma_f32_16x16x32_bf16(a[i], b[j], acc[i][j], 0, 0, 0);
        }
        __syncthreads();
    }
    float cs[4];
#pragma unroll
    for (int j = 0; j < 4; ++j) {
        const float bj = b1[j * 16 + lrow];
        float sv = 0.f;
#pragma unroll
        for (int i = 0; i < 2; ++i)
#pragma unroll
            for (int r = 0; r < 4; ++r) sv += fmaxf(acc[i][j][r] + bj, 0.f);
        cs[j] = sv;
    }
#pragma unroll
    for (int j = 0; j < 4; ++j) {
        cs[j] += __shfl_xor(cs[j], 16);
        cs[j] += __shfl_xor(cs[j], 32);
    }
    if (lkg == 0) {
#pragma unroll
        for (int j = 0; j < 4; ++j) red[w][j * 16 + lrow] = cs[j];
    }
    __syncthreads();
    if (tid < 64) {
        float t = red[0][tid] + red[1][tid] + red[2][tid] + red[3][tid];
        float h0 = t * W2[tid * 2 + 0];
        float h1 = t * W2[tid * 2 + 1];
#pragma unroll
        for (int off = 32; off > 0; off >>= 1) {
            h0 += __shfl_down(h0, off);
            h1 += __shfl_down(h1, off);
        }
        if (tid == 0) {
            partials[blockIdx.x * 2 + 0] = h0;
            partials[blockIdx.x * 2 + 1] = h1;
        }
    }
}

__global__ void finalize(const float* __restrict__ partials,
                         const float* __restrict__ b2, float* __restrict__ out) {
    const int l = threadIdx.x;
    float h0 = 0.f, h1 = 0.f;
    for (int i = l; i < 128; i += 64) {
        h0 += partials[2 * i + 0];
        h1 += partials[2 * i + 1];
    }
#pragma unroll
    for (int off = 32; off > 0; off >>= 1) {
        h0 += __shfl_down(h0, off);
        h1 += __shfl_down(h1, off);
    }
    if (l == 0) {
        h0 += (float)N_NODES * b2[0];
        h1 += (float)N_NODES * b2[1];
        const float m = fmaxf(h0, h1);
        const float e0 = __expf(h0 - m), e1 = __expf(h1 - m);
        out[(size_t)N_NODES * DIM + 0] = e0 / (e0 + e1);
        out[(size_t)N_NODES * DIM + 1] = e1 / (e0 + e1);
    }
}

extern "C" void kernel_launch(void* const* d_in, const int* in_sizes, int n_in,
                              void* d_out, int out_size, void* d_ws, size_t ws_size,
                              hipStream_t stream) {
    const float* X = (const float*)d_in[0];
    const int* in_idx = (const int*)d_in[1];
    const int* in_edge = (const int*)d_in[2];
    const float* in_mask = (const float*)d_in[3];
    const int* out_idx = (const int*)d_in[4];
    const int* out_edge = (const int*)d_in[5];
    const float* out_mask = (const float*)d_in[6];
    const float* Eemb = (const float*)d_in[7];
    const float* W_nb = (const float*)d_in[8];
    const float* b_nb = (const float*)d_in[9];
    const float* W_node = (const float*)d_in[10];
    // d_in[11] = b_node: softmax-invariant -> unused
    const float* attenW = (const float*)d_in[12];
    const float* W1 = (const float*)d_in[13];
    const float* b1 = (const float*)d_in[14];
    const float* W2 = (const float*)d_in[15];
    const float* b2 = (const float*)d_in[16];
    float* out = (float*)d_out;

    char* ws = (char*)d_ws;
    // Overlays (stream-ordered): Zh+EZf dead after gather_fused -> Hh reuses.
    u16* Zh = (u16*)ws;                          // 8 MiB   [0, 8M)
    float* EZf = (float*)(ws + 8388608);         // 8 MiB   [8M, 16M)
    u16* Hh = (u16*)ws;                          // 8 MiB   [0, 8M) reuse
    u16* REPh = (u16*)(ws + 16777216);           // 12.58 MiB
    u16* Xh = (u16*)(ws + 29360128);             // 8 MiB
    u16* WnbTh2 = (u16*)(ws + 37748736);         // 192 KiB (256x384)
    u16* Mhi = (u16*)(ws + 37945344);            // 192 KiB (384x256)
    u16* Mlo = (u16*)(ws + 38141952);            // 192 KiB
    u16* W1h = (u16*)(ws + 38338560);            // 32 KiB
    float* partials = (float*)(ws + 38371328);   // 1 KiB

    prep<<<2560, 256, 0, stream>>>(X, W_nb, W1, W_node, attenW, Eemb,
                                   Xh, WnbTh2, W1h, Mhi, Mlo);
    gemm_z<<<dim3(128, 3), 256, 0, stream>>>(Xh, Mhi, Mlo, Zh, EZf);
    gather_fused<<<N_NODES / 4, 256, 0, stream>>>(Xh, Zh, EZf, in_idx, in_edge,
                                                  in_mask, out_idx, out_edge,
                                                  out_mask, REPh);
    gemm_h<<<dim3(128, 2), 256, 0, stream>>>(REPh, WnbTh2, X, b_nb, out, Hh);
    mlp_mfma<<<N_NODES / 128, 256, 0, stream>>>(Hh, W1h, b1, W2, partials);
    finalize<<<1, 64, 0, stream>>>(partials, b2, out);
}